// Round 6
// baseline (495.136 us; speedup 1.0000x reference)
//
#include <hip/hip_runtime.h>

#define HH 56
#define WW2 56
#define WS 7
#define SHIFT 3
#define HEADS 4
#define DIM 128
#define NTOK 49
#define BATCH 64
#define TOKENS (BATCH*HH*WW2)   // 200704
#define NWIN 64                 // windows per image (8x8)
#define WINDOWS (BATCH*NWIN)    // 4096

typedef __bf16 bf16x8 __attribute__((ext_vector_type(8)));
typedef float  f32x4  __attribute__((ext_vector_type(4)));

// Native RTNE f32->bf16 (lowers to v_cvt_pk_bf16_f32 on gfx950).
__device__ __forceinline__ unsigned short f2bf(float f) {
  union { __bf16 b; unsigned short u; } cv;
  cv.b = (__bf16)f;
  return cv.u;
}

__device__ __forceinline__ void st4(unsigned short* p, float a, float b, float c, float d) {
  ushort4 pk; pk.x = f2bf(a); pk.y = f2bf(b); pk.z = f2bf(c); pk.w = f2bf(d);
  *(ushort4*)p = pk;
}

__device__ __forceinline__ int reg3(int g) { return g >= 53 ? 2 : (g >= 49 ? 1 : 0); }

// ---------------- weight prep: transpose + bf16 ----------------
__global__ __launch_bounds__(256) void k_prep(
    const float* __restrict__ qkv_w, const float* __restrict__ proj_w,
    const float* __restrict__ w1, const float* __restrict__ w2,
    unsigned short* __restrict__ qkvwT, unsigned short* __restrict__ projwT,
    unsigned short* __restrict__ w1T, unsigned short* __restrict__ w2T)
{
  int idx = blockIdx.x * 256 + threadIdx.x;
  if (idx < 49152) {                       // qkv_w [128][384] -> qkvwT [384][128]
    int n = idx >> 7, k = idx & 127;
    qkvwT[idx] = f2bf(qkv_w[k * 384 + n]);
  } else if (idx < 65536) {                // proj_w [128][128] -> projwT [128][128]
    int i = idx - 49152; int n = i >> 7, k = i & 127;
    projwT[i] = f2bf(proj_w[k * 128 + n]);
  } else if (idx < 131072) {               // mlp_w1 [128][512] -> w1T [512][128]
    int i = idx - 65536; int n = i >> 7, k = i & 127;
    w1T[i] = f2bf(w1[k * 512 + n]);
  } else {                                 // mlp_w2 [512][128] -> w2T [128][512]
    int i = idx - 131072; int n = i >> 9, k = i & 511;
    w2T[i] = f2bf(w2[k * 128 + n]);
  }
}

// ---------------- bias+mask table: [cls][head][qtoken 64][ktoken 64] fp32 ----------------
__global__ __launch_bounds__(256) void k_tbl(const float* __restrict__ rpb, float* __restrict__ tbl)
{
  int idx = blockIdx.x * 256 + threadIdx.x;   // 65536 entries
  int kt = idx & 63, qt = (idx >> 6) & 63, h = (idx >> 12) & 3, cls = idx >> 14;
  float v;
  if (qt >= NTOK || kt >= NTOK) v = -3e38f;
  else {
    int qi = qt / 7, qj = qt % 7, ki = kt / 7, kj = kt % 7;
    int bi = (cls & 2) ? 49 : 0, bj = (cls & 1) ? 49 : 0;
    int rq = reg3(bi + qi) * 3 + reg3(bj + qj);
    int rk = reg3(bi + ki) * 3 + reg3(bj + kj);
    v = rpb[((qi - ki + 6) * 13 + (qj - kj + 6)) * HEADS + h] + (rq != rk ? -100.0f : 0.0f);
  }
  tbl[idx] = v;
}

// ---------------- fused LN1 + window attention, 8 waves (512 thr) ----------------
__global__ __launch_bounds__(512, 4) void k_attn(
    const float* __restrict__ x,
    const float* __restrict__ n1w, const float* __restrict__ n1b,
    const unsigned short* __restrict__ qkvwT,
    const float* __restrict__ qkv_b,
    const unsigned short* __restrict__ projwT,
    const float* __restrict__ proj_b,
    const float* __restrict__ tbl,
    unsigned short* __restrict__ attn_out)
{
  __shared__ __align__(16) unsigned short s_x[64 * 136];   // x tile; then PV [token][d]
  __shared__ __align__(16) unsigned short s_qk[64 * 264];  // q|k [token][dim]; then P [qtok][ktok] per head
  __shared__ __align__(16) unsigned short s_vT[128 * 72];  // v^T [d][token]; then proj-out stage

  int tid = threadIdx.x;
  int wave = tid >> 6;          // 0..7
  int lane = tid & 63;
  int l = lane & 15, g = lane >> 4;
  int win = blockIdx.x;
  int wi = (win & 63) >> 3, wj = win & 7;
  int bi = win >> 6;

  // ---- phase 0: gather shifted rows of x, LN1 -> bf16 s_x; zero pad rows ----
  {
    float2 wv1 = *(const float2*)(n1w + lane * 2);
    float2 bv1 = *(const float2*)(n1b + lane * 2);
    float2 vr[7];
    #pragma unroll
    for (int rr = 0; rr < 7; ++rr) {       // issue all row loads up front
      int row = wave + rr * 8;
      if (row < NTOK) {
        int ti = row / 7, tj = row % 7;
        int i = wi * WS + ti + SHIFT; if (i >= HH) i -= HH;
        int j = wj * WS + tj + SHIFT; if (j >= WW2) j -= WW2;
        const float* xp = x + ((size_t)(bi * (HH * WW2) + i * WW2 + j)) * DIM;
        vr[rr] = *(const float2*)(xp + lane * 2);
      }
    }
    #pragma unroll
    for (int rr = 0; rr < 7; ++rr) {
      int row = wave + rr * 8;
      if (row < NTOK) {
        float2 v = vr[rr];
        float s = v.x + v.y, sq = v.x * v.x + v.y * v.y;
        #pragma unroll
        for (int off = 32; off; off >>= 1) {
          s += __shfl_xor(s, off);
          sq += __shfl_xor(sq, off);
        }
        float mean = s * (1.0f / DIM);
        float var = sq * (1.0f / DIM) - mean * mean;
        float rs = rsqrtf(var + 1e-5f);
        float y0 = (v.x - mean) * rs * wv1.x + bv1.x;
        float y1 = (v.y - mean) * rs * wv1.y + bv1.y;
        unsigned pack = ((unsigned)f2bf(y1) << 16) | (unsigned)f2bf(y0);
        *(unsigned*)&s_x[row * 136 + lane * 2] = pack;
      }
    }
  }
  for (int idx = tid; idx < 15 * 17; idx += 512) {
    int row = 49 + idx / 17, seg = idx % 17;
    *(uint4*)&s_x[row * 136 + seg * 8] = make_uint4(0, 0, 0, 0);
  }
  __syncthreads();

  // ---- phase 1: QKV^T GEMM: A=weights [wcol][k], B=x [token][k], D=[wcol][token] ----
  bf16x8 xf[4][4];   // [nt(token tile)][kk]
  #pragma unroll
  for (int nt = 0; nt < 4; ++nt)
    #pragma unroll
    for (int kk = 0; kk < 4; ++kk)
      xf[nt][kk] = *(const bf16x8*)&s_x[(nt * 16 + l) * 136 + kk * 32 + g * 8];

  #pragma unroll
  for (int wti = 0; wti < 3; ++wti) {
    int wt = wave * 3 + wti;                 // m-tile over 384 wcols, 0..23
    bf16x8 wf[4];
    #pragma unroll
    for (int kk = 0; kk < 4; ++kk)
      wf[kk] = *(const bf16x8*)(qkvwT + (size_t)(wt * 16 + l) * DIM + kk * 32 + g * 8);
    f32x4 acc[4];
    #pragma unroll
    for (int nt = 0; nt < 4; ++nt) acc[nt] = (f32x4){0.f, 0.f, 0.f, 0.f};
    #pragma unroll
    for (int kk = 0; kk < 4; ++kk)
      #pragma unroll
      for (int nt = 0; nt < 4; ++nt)
        acc[nt] = __builtin_amdgcn_mfma_f32_16x16x32_bf16(wf[kk], xf[nt][kk], acc[nt], 0, 0, 0);
    float4 b4 = *(const float4*)(qkv_b + wt * 16 + g * 4);
    if (wt < 16) {           // q (wt<8, cols 0-127) and k (cols 128-255): col = wt*16+g*4
      float sc = wt < 8 ? 0.17677669529663687f : 1.0f;
      #pragma unroll
      for (int nt = 0; nt < 4; ++nt)
        st4(&s_qk[(nt * 16 + l) * 264 + wt * 16 + g * 4],
            (acc[nt][0] + b4.x) * sc, (acc[nt][1] + b4.y) * sc,
            (acc[nt][2] + b4.z) * sc, (acc[nt][3] + b4.w) * sc);
    } else {                 // v -> v^T [d][token]
      int d0 = wt * 16 - 256 + g * 4;
      #pragma unroll
      for (int nt = 0; nt < 4; ++nt) {
        s_vT[(d0 + 0) * 72 + nt * 16 + l] = f2bf(acc[nt][0] + b4.x);
        s_vT[(d0 + 1) * 72 + nt * 16 + l] = f2bf(acc[nt][1] + b4.y);
        s_vT[(d0 + 2) * 72 + nt * 16 + l] = f2bf(acc[nt][2] + b4.z);
        s_vT[(d0 + 3) * 72 + nt * 16 + l] = f2bf(acc[nt][3] + b4.w);
      }
    }
  }
  __syncthreads();

  // ---- phase 2: S^T = K.Q^T, table C-init; in-reg softmax; P [qtok][ktok] ----
  int h = wave >> 1, qh = wave & 1;          // head, qtok-half
  bf16x8 kf[4], qf[2];
  #pragma unroll
  for (int mt = 0; mt < 4; ++mt)
    kf[mt] = *(const bf16x8*)&s_qk[(mt * 16 + l) * 264 + 128 + h * 32 + g * 8];
  #pragma unroll
  for (int nt2 = 0; nt2 < 2; ++nt2) {
    int nt = qh * 2 + nt2;
    qf[nt2] = *(const bf16x8*)&s_qk[(nt * 16 + l) * 264 + h * 32 + g * 8];
  }
  __syncthreads();   // all q/k fragment reads done; s_qk reusable as P

  int clsid = ((wi == 7) ? 2 : 0) | ((wj == 7) ? 1 : 0);
  const float* tb = tbl + ((clsid * 4 + h) << 12);
  f32x4 sc[4][2];    // [mt=ktok tile][nt2=qtok tile half]
  #pragma unroll
  for (int nt2 = 0; nt2 < 2; ++nt2) {
    int nt = qh * 2 + nt2;
    #pragma unroll
    for (int mt = 0; mt < 4; ++mt) {
      f32x4 ci = *(const f32x4*)(tb + (nt * 16 + l) * 64 + mt * 16 + g * 4);
      sc[mt][nt2] = __builtin_amdgcn_mfma_f32_16x16x32_bf16(kf[mt], qf[nt2], ci, 0, 0, 0);
    }
  }

  #pragma unroll
  for (int nt2 = 0; nt2 < 2; ++nt2) {
    int nt = qh * 2 + nt2;
    float m = sc[0][nt2][0];
    #pragma unroll
    for (int mt = 0; mt < 4; ++mt)
      #pragma unroll
      for (int rr = 0; rr < 4; ++rr) m = fmaxf(m, sc[mt][nt2][rr]);
    m = fmaxf(m, __shfl_xor(m, 16));
    m = fmaxf(m, __shfl_xor(m, 32));
    float ssum = 0.f;
    #pragma unroll
    for (int mt = 0; mt < 4; ++mt)
      #pragma unroll
      for (int rr = 0; rr < 4; ++rr) {
        float e = __expf(sc[mt][nt2][rr] - m);
        sc[mt][nt2][rr] = e;
        ssum += e;
      }
    ssum += __shfl_xor(ssum, 16);
    ssum += __shfl_xor(ssum, 32);
    float inv = 1.0f / ssum;
    #pragma unroll
    for (int mt = 0; mt < 4; ++mt)
      st4(&s_qk[(nt * 16 + l) * 264 + h * 64 + mt * 16 + g * 4],
          sc[mt][nt2][0] * inv, sc[mt][nt2][1] * inv, sc[mt][nt2][2] * inv, sc[mt][nt2][3] * inv);
  }
  __syncthreads();   // P is cross-wave now (PV reads all 4 nt per head)

  // ---- phase 3: PV^T: A=v^T [d][ktok], B=P [qtok][ktok], D=[d][qtok] -> s_x[token][d] ----
  int dt = qh;       // d-subtile within head
  bf16x8 vf[2], pf[4][2];
  #pragma unroll
  for (int kk = 0; kk < 2; ++kk)
    vf[kk] = *(const bf16x8*)&s_vT[(h * 32 + dt * 16 + l) * 72 + kk * 32 + g * 8];
  #pragma unroll
  for (int nt = 0; nt < 4; ++nt)
    #pragma unroll
    for (int kk = 0; kk < 2; ++kk)
      pf[nt][kk] = *(const bf16x8*)&s_qk[(nt * 16 + l) * 264 + h * 64 + kk * 32 + g * 8];
  #pragma unroll
  for (int nt = 0; nt < 4; ++nt) {
    f32x4 a = (f32x4){0.f, 0.f, 0.f, 0.f};
    a = __builtin_amdgcn_mfma_f32_16x16x32_bf16(vf[0], pf[nt][0], a, 0, 0, 0);
    a = __builtin_amdgcn_mfma_f32_16x16x32_bf16(vf[1], pf[nt][1], a, 0, 0, 0);
    st4(&s_x[(nt * 16 + l) * 136 + h * 32 + dt * 16 + g * 4], a[0], a[1], a[2], a[3]);
  }
  __syncthreads();

  // ---- phase 4: proj^T: A=projW^T [pcol][d], B=PV [token][d], D=[pcol][token] ----
  unsigned short* stage = s_vT;   // 64x136 fits in 128x72 region
  bf16x8 of[4][4];
  #pragma unroll
  for (int nt = 0; nt < 4; ++nt)
    #pragma unroll
    for (int kk = 0; kk < 4; ++kk)
      of[nt][kk] = *(const bf16x8*)&s_x[(nt * 16 + l) * 136 + kk * 32 + g * 8];
  {
    int wt = wave;               // 0..7 covers 128 pcols
    bf16x8 wf[4];
    #pragma unroll
    for (int kk = 0; kk < 4; ++kk)
      wf[kk] = *(const bf16x8*)(projwT + (size_t)(wt * 16 + l) * DIM + kk * 32 + g * 8);
    f32x4 acc[4];
    #pragma unroll
    for (int nt = 0; nt < 4; ++nt) acc[nt] = (f32x4){0.f, 0.f, 0.f, 0.f};
    #pragma unroll
    for (int kk = 0; kk < 4; ++kk)
      #pragma unroll
      for (int nt = 0; nt < 4; ++nt)
        acc[nt] = __builtin_amdgcn_mfma_f32_16x16x32_bf16(wf[kk], of[nt][kk], acc[nt], 0, 0, 0);
    float4 b4 = *(const float4*)(proj_b + wt * 16 + g * 4);
    #pragma unroll
    for (int nt = 0; nt < 4; ++nt)
      st4(&stage[(nt * 16 + l) * 136 + wt * 16 + g * 4],
          acc[nt][0] + b4.x, acc[nt][1] + b4.y, acc[nt][2] + b4.z, acc[nt][3] + b4.w);
  }
  __syncthreads();

  unsigned short* outp = attn_out + (size_t)win * (NTOK * DIM);
  for (int idx = tid; idx < NTOK * 16; idx += 512) {
    int row = idx >> 4, seg = idx & 15;
    *(uint4*)(outp + idx * 8) = *(const uint4*)&stage[row * 136 + seg * 8];
  }
}

// gelu via sigmoid form: 0.5x(1+tanh(y)) = x * sigmoid(2y), y = 0.79788456(x+0.044715x^3)
__device__ __forceinline__ float gelu_f(float x) {
  float x2 = x * x;
  float t = x * __builtin_fmaf(x2, -0.10294429f, -2.3022077f);
  float e = __builtin_amdgcn_exp2f(t);
  return x * __builtin_amdgcn_rcpf(1.0f + e);
}

// ---------------- fused residual+LN2+MLP, 8 waves (512 thr) ----------------
// io = z + gelu(ln2(z)@w1+b1)@w2 + b2, z = x + attn(gathered), z in REGISTERS.
// Wave-split: each wave owns 16 of the 128 output cols (col0 = wave*16+g*4):
// one wt-tile per chunk in GEMM1, fixed pcol-tile in GEMM2, 16 cols of the
// prologue/epilogue fragment. Per-wave serial work halves vs the 4-wave
// version; resident waves/CU unchanged -> better latency overlap.
__global__ __launch_bounds__(512, 4) void k_mlp(
    const float* __restrict__ x, const unsigned short* __restrict__ attn,
    const float* __restrict__ n2w, const float* __restrict__ n2b,
    const unsigned short* __restrict__ w1T, const float* __restrict__ b1,
    const unsigned short* __restrict__ w2T, const float* __restrict__ b2,
    float* __restrict__ io)
{
  __shared__ __align__(16) unsigned short s_t[2][64 * 136];
  __shared__ float s_part[64][8][2];
  int tid = threadIdx.x;
  int wave = tid >> 6;          // 0..7
  int lane = tid & 63;
  int l = lane & 15, g = lane >> 4;
  size_t m0 = (size_t)blockIdx.x * 64;
  int col0 = wave * 16 + g * 4;

  // ---- prologue: residual + LN2 ----
  float4 xz[4];
  float sA[4], sQ[4];
  #pragma unroll
  for (int nt = 0; nt < 4; ++nt) {
    int row = nt * 16 + l;
    int t = (int)m0 + row;
    int bi = t / (HH * WW2);
    int r = t % (HH * WW2);
    int i = r / WW2, j = r % WW2;
    int si = i >= SHIFT ? i - SHIFT : i + (HH - SHIFT);
    int sj = j >= SHIFT ? j - SHIFT : j + (WW2 - SHIFT);
    int win = bi * NWIN + (si / WS) * 8 + (sj / WS);
    int tok = (si % WS) * WS + (sj % WS);
    float4 xv = *(const float4*)(x + (size_t)t * DIM + col0);
    ushort4 av = *(const ushort4*)(attn + ((size_t)(win * NTOK + tok)) * DIM + col0);
    float4 z;
    z.x = xv.x + __uint_as_float((unsigned)av.x << 16);
    z.y = xv.y + __uint_as_float((unsigned)av.y << 16);
    z.z = xv.z + __uint_as_float((unsigned)av.z << 16);
    z.w = xv.w + __uint_as_float((unsigned)av.w << 16);
    xz[nt] = z;
    float s = z.x + z.y + z.z + z.w;
    float sq = z.x * z.x + z.y * z.y + z.z * z.z + z.w * z.w;
    s += __shfl_xor(s, 16); s += __shfl_xor(s, 32);
    sq += __shfl_xor(sq, 16); sq += __shfl_xor(sq, 32);
    sA[nt] = s; sQ[nt] = sq;   // per-row partial over this wave's 16 cols
  }
  if (g == 0) {
    #pragma unroll
    for (int nt = 0; nt < 4; ++nt) {
      s_part[nt * 16 + l][wave][0] = sA[nt];
      s_part[nt * 16 + l][wave][1] = sQ[nt];
    }
  }
  __syncthreads();
  float4 wv0 = *(const float4*)(n2w + col0);
  float4 bv0 = *(const float4*)(n2b + col0);
  #pragma unroll
  for (int nt = 0; nt < 4; ++nt) {
    int row = nt * 16 + l;
    float s = 0.f, sq = 0.f;
    #pragma unroll
    for (int wv = 0; wv < 8; ++wv) { s += s_part[row][wv][0]; sq += s_part[row][wv][1]; }
    float mean = s * (1.0f / DIM);
    float var = sq * (1.0f / DIM) - mean * mean;
    float rs = rsqrtf(var + 1e-5f);
    float4 z0 = xz[nt];
    st4(&s_t[1][row * 136 + col0],
        (z0.x - mean) * rs * wv0.x + bv0.x, (z0.y - mean) * rs * wv0.y + bv0.y,
        (z0.z - mean) * rs * wv0.z + bv0.z, (z0.w - mean) * rs * wv0.w + bv0.w);
  }
  __syncthreads();

  bf16x8 hf[4][4];
  #pragma unroll
  for (int nt = 0; nt < 4; ++nt)
    #pragma unroll
    for (int kk = 0; kk < 4; ++kk)
      hf[nt][kk] = *(const bf16x8*)&s_t[1][(nt * 16 + l) * 136 + kk * 32 + g * 8];

  f32x4 o[4];
  #pragma unroll
  for (int nt = 0; nt < 4; ++nt) o[nt] = (f32x4){0.f, 0.f, 0.f, 0.f};

  // Double-buffered s_t (same hazard argument as 4-wave version: first write
  // into s_t[1] at c=1 is fenced by barrier(0); buffer p rewritten at c+2 is
  // fenced by barrier(c+1) which no wave passes before its GEMM2(c) reads).
  for (int c = 0; c < 4; ++c) {
    unsigned short* buf = s_t[c & 1];
    // GEMM1^T chunk: wave's 16 w1cols; D[w1col][token], gelu, store buf
    {
      int n0 = c * 128 + wave * 16;
      bf16x8 wf[4];
      #pragma unroll
      for (int kk = 0; kk < 4; ++kk)
        wf[kk] = *(const bf16x8*)(w1T + (size_t)(n0 + l) * DIM + kk * 32 + g * 8);
      f32x4 acc[4];
      #pragma unroll
      for (int nt = 0; nt < 4; ++nt) acc[nt] = (f32x4){0.f, 0.f, 0.f, 0.f};
      #pragma unroll
      for (int kk = 0; kk < 4; ++kk)
        #pragma unroll
        for (int nt = 0; nt < 4; ++nt)
          acc[nt] = __builtin_amdgcn_mfma_f32_16x16x32_bf16(wf[kk], hf[nt][kk], acc[nt], 0, 0, 0);
      float4 b4 = *(const float4*)(b1 + n0 + g * 4);
      #pragma unroll
      for (int nt = 0; nt < 4; ++nt)
        st4(&buf[(nt * 16 + l) * 136 + wave * 16 + g * 4],
            gelu_f(acc[nt][0] + b4.x), gelu_f(acc[nt][1] + b4.y),
            gelu_f(acc[nt][2] + b4.z), gelu_f(acc[nt][3] + b4.w));
    }
    __syncthreads();
    // GEMM2^T chunk: o[pcol=wave tile][token] += w2 chunk . t chunk
    #pragma unroll
    for (int kk = 0; kk < 4; ++kk) {
      bf16x8 tf[4];
      #pragma unroll
      for (int nt = 0; nt < 4; ++nt)
        tf[nt] = *(const bf16x8*)&buf[(nt * 16 + l) * 136 + kk * 32 + g * 8];
      bf16x8 wf2 = *(const bf16x8*)(w2T + (size_t)(wave * 16 + l) * 512 + c * 128 + kk * 32 + g * 8);
      #pragma unroll
      for (int nt = 0; nt < 4; ++nt)
        o[nt] = __builtin_amdgcn_mfma_f32_16x16x32_bf16(wf2, tf[nt], o[nt], 0, 0, 0);
    }
  }

  // ---- epilogue: io = z + mlp_out + b2, single store, no load ----
  {
    float4 b4 = *(const float4*)(b2 + col0);
    #pragma unroll
    for (int nt = 0; nt < 4; ++nt) {
      float4 z = xz[nt];
      float4 pv;
      pv.x = z.x + o[nt][0] + b4.x;
      pv.y = z.y + o[nt][1] + b4.y;
      pv.z = z.z + o[nt][2] + b4.z;
      pv.w = z.w + o[nt][3] + b4.w;
      *(float4*)(io + (m0 + nt * 16 + l) * DIM + col0) = pv;
    }
  }
}

extern "C" void kernel_launch(void* const* d_in, const int* in_sizes, int n_in,
                              void* d_out, int out_size, void* d_ws, size_t ws_size,
                              hipStream_t stream) {
  const float* x       = (const float*)d_in[0];
  const float* qkv_w   = (const float*)d_in[1];
  const float* qkv_b   = (const float*)d_in[2];
  const float* proj_w  = (const float*)d_in[3];
  const float* proj_b  = (const float*)d_in[4];
  const float* rpb     = (const float*)d_in[5];
  const float* n1w     = (const float*)d_in[6];
  const float* n1b     = (const float*)d_in[7];
  const float* n2w     = (const float*)d_in[8];
  const float* n2b     = (const float*)d_in[9];
  const float* mlp_w1  = (const float*)d_in[10];
  const float* mlp_b1  = (const float*)d_in[11];
  const float* mlp_w2  = (const float*)d_in[12];
  const float* mlp_b2  = (const float*)d_in[13];
  float* out = (float*)d_out;

  char* ws = (char*)d_ws;
  const size_t TOKB = (size_t)TOKENS * DIM * 2;     // 51,380,224 B
  unsigned short* attn_o = (unsigned short*)(ws);
  unsigned short* qkvwT  = (unsigned short*)(ws + TOKB);
  unsigned short* projwT = (unsigned short*)(ws + TOKB + 98304);
  unsigned short* w1T    = (unsigned short*)(ws + TOKB + 98304 + 32768);
  unsigned short* w2T    = (unsigned short*)(ws + TOKB + 98304 + 32768 + 131072);
  float*          tbl    = (float*)(ws + TOKB + 98304 + 32768 + 131072 + 131072);  // 262144 B

  k_prep<<<768, 256, 0, stream>>>(qkv_w, proj_w, mlp_w1, mlp_w2, qkvwT, projwT, w1T, w2T);
  k_tbl<<<256, 256, 0, stream>>>(rpb, tbl);
  k_attn<<<WINDOWS, 512, 0, stream>>>(x, n1w, n1b, qkvwT, qkv_b, projwT, proj_b, tbl, attn_o);
  k_mlp<<<TOKENS / 64, 512, 0, stream>>>(x, attn_o, n2w, n2b, w1T, mlp_b1, w2T, mlp_b2, out);
}

// Round 7
// 474.913 us; speedup vs baseline: 1.0426x; 1.0426x over previous
//
#include <hip/hip_runtime.h>

#define HH 56
#define WW2 56
#define WS 7
#define SHIFT 3
#define HEADS 4
#define DIM 128
#define NTOK 49
#define BATCH 64
#define TOKENS (BATCH*HH*WW2)   // 200704
#define NWIN 64                 // windows per image (8x8)
#define WINDOWS (BATCH*NWIN)    // 4096

typedef __bf16 bf16x8 __attribute__((ext_vector_type(8)));
typedef float  f32x4  __attribute__((ext_vector_type(4)));

// Native RTNE f32->bf16 (lowers to v_cvt_pk_bf16_f32 on gfx950).
__device__ __forceinline__ unsigned short f2bf(float f) {
  union { __bf16 b; unsigned short u; } cv;
  cv.b = (__bf16)f;
  return cv.u;
}

__device__ __forceinline__ void st4(unsigned short* p, float a, float b, float c, float d) {
  ushort4 pk; pk.x = f2bf(a); pk.y = f2bf(b); pk.z = f2bf(c); pk.w = f2bf(d);
  *(ushort4*)p = pk;
}

__device__ __forceinline__ int reg3(int g) { return g >= 53 ? 2 : (g >= 49 ? 1 : 0); }

// ---------------- weight prep: transpose + bf16 ----------------
__global__ __launch_bounds__(256) void k_prep(
    const float* __restrict__ qkv_w, const float* __restrict__ proj_w,
    const float* __restrict__ w1, const float* __restrict__ w2,
    unsigned short* __restrict__ qkvwT, unsigned short* __restrict__ projwT,
    unsigned short* __restrict__ w1T, unsigned short* __restrict__ w2T)
{
  int idx = blockIdx.x * 256 + threadIdx.x;
  if (idx < 49152) {                       // qkv_w [128][384] -> qkvwT [384][128]
    int n = idx >> 7, k = idx & 127;
    qkvwT[idx] = f2bf(qkv_w[k * 384 + n]);
  } else if (idx < 65536) {                // proj_w [128][128] -> projwT [128][128]
    int i = idx - 49152; int n = i >> 7, k = i & 127;
    projwT[i] = f2bf(proj_w[k * 128 + n]);
  } else if (idx < 131072) {               // mlp_w1 [128][512] -> w1T [512][128]
    int i = idx - 65536; int n = i >> 7, k = i & 127;
    w1T[i] = f2bf(w1[k * 512 + n]);
  } else {                                 // mlp_w2 [512][128] -> w2T [128][512]
    int i = idx - 131072; int n = i >> 9, k = i & 511;
    w2T[i] = f2bf(w2[k * 128 + n]);
  }
}

// ---------------- bias+mask table: [cls][head][qtoken 64][ktoken 64] fp32 ----------------
__global__ __launch_bounds__(256) void k_tbl(const float* __restrict__ rpb, float* __restrict__ tbl)
{
  int idx = blockIdx.x * 256 + threadIdx.x;   // 65536 entries
  int kt = idx & 63, qt = (idx >> 6) & 63, h = (idx >> 12) & 3, cls = idx >> 14;
  float v;
  if (qt >= NTOK || kt >= NTOK) v = -3e38f;
  else {
    int qi = qt / 7, qj = qt % 7, ki = kt / 7, kj = kt % 7;
    int bi = (cls & 2) ? 49 : 0, bj = (cls & 1) ? 49 : 0;
    int rq = reg3(bi + qi) * 3 + reg3(bj + qj);
    int rk = reg3(bi + ki) * 3 + reg3(bj + kj);
    v = rpb[((qi - ki + 6) * 13 + (qj - kj + 6)) * HEADS + h] + (rq != rk ? -100.0f : 0.0f);
  }
  tbl[idx] = v;
}

// ---------------- fused LN1 + window attention, 8 waves (512 thr) ----------------
__global__ __launch_bounds__(512, 4) void k_attn(
    const float* __restrict__ x,
    const float* __restrict__ n1w, const float* __restrict__ n1b,
    const unsigned short* __restrict__ qkvwT,
    const float* __restrict__ qkv_b,
    const unsigned short* __restrict__ projwT,
    const float* __restrict__ proj_b,
    const float* __restrict__ tbl,
    unsigned short* __restrict__ attn_out)
{
  __shared__ __align__(16) unsigned short s_x[64 * 136];   // x tile; then PV [token][d]
  __shared__ __align__(16) unsigned short s_qk[64 * 264];  // q|k [token][dim]; then P [qtok][ktok] per head
  __shared__ __align__(16) unsigned short s_vT[128 * 72];  // v^T [d][token]; then proj-out stage

  int tid = threadIdx.x;
  int wave = tid >> 6;          // 0..7
  int lane = tid & 63;
  int l = lane & 15, g = lane >> 4;
  int win = blockIdx.x;
  int wi = (win & 63) >> 3, wj = win & 7;
  int bi = win >> 6;

  // ---- phase 0: gather shifted rows of x, LN1 -> bf16 s_x; zero pad rows ----
  {
    float2 wv1 = *(const float2*)(n1w + lane * 2);
    float2 bv1 = *(const float2*)(n1b + lane * 2);
    float2 vr[7];
    #pragma unroll
    for (int rr = 0; rr < 7; ++rr) {       // issue all row loads up front
      int row = wave + rr * 8;
      if (row < NTOK) {
        int ti = row / 7, tj = row % 7;
        int i = wi * WS + ti + SHIFT; if (i >= HH) i -= HH;
        int j = wj * WS + tj + SHIFT; if (j >= WW2) j -= WW2;
        const float* xp = x + ((size_t)(bi * (HH * WW2) + i * WW2 + j)) * DIM;
        vr[rr] = *(const float2*)(xp + lane * 2);
      }
    }
    #pragma unroll
    for (int rr = 0; rr < 7; ++rr) {
      int row = wave + rr * 8;
      if (row < NTOK) {
        float2 v = vr[rr];
        float s = v.x + v.y, sq = v.x * v.x + v.y * v.y;
        #pragma unroll
        for (int off = 32; off; off >>= 1) {
          s += __shfl_xor(s, off);
          sq += __shfl_xor(sq, off);
        }
        float mean = s * (1.0f / DIM);
        float var = sq * (1.0f / DIM) - mean * mean;
        float rs = rsqrtf(var + 1e-5f);
        float y0 = (v.x - mean) * rs * wv1.x + bv1.x;
        float y1 = (v.y - mean) * rs * wv1.y + bv1.y;
        unsigned pack = ((unsigned)f2bf(y1) << 16) | (unsigned)f2bf(y0);
        *(unsigned*)&s_x[row * 136 + lane * 2] = pack;
      }
    }
  }
  for (int idx = tid; idx < 15 * 17; idx += 512) {
    int row = 49 + idx / 17, seg = idx % 17;
    *(uint4*)&s_x[row * 136 + seg * 8] = make_uint4(0, 0, 0, 0);
  }
  __syncthreads();

  // ---- phase 1: QKV^T GEMM: A=weights [wcol][k], B=x [token][k], D=[wcol][token] ----
  bf16x8 xf[4][4];   // [nt(token tile)][kk]
  #pragma unroll
  for (int nt = 0; nt < 4; ++nt)
    #pragma unroll
    for (int kk = 0; kk < 4; ++kk)
      xf[nt][kk] = *(const bf16x8*)&s_x[(nt * 16 + l) * 136 + kk * 32 + g * 8];

  #pragma unroll
  for (int wti = 0; wti < 3; ++wti) {
    int wt = wave * 3 + wti;                 // m-tile over 384 wcols, 0..23
    bf16x8 wf[4];
    #pragma unroll
    for (int kk = 0; kk < 4; ++kk)
      wf[kk] = *(const bf16x8*)(qkvwT + (size_t)(wt * 16 + l) * DIM + kk * 32 + g * 8);
    f32x4 acc[4];
    #pragma unroll
    for (int nt = 0; nt < 4; ++nt) acc[nt] = (f32x4){0.f, 0.f, 0.f, 0.f};
    #pragma unroll
    for (int kk = 0; kk < 4; ++kk)
      #pragma unroll
      for (int nt = 0; nt < 4; ++nt)
        acc[nt] = __builtin_amdgcn_mfma_f32_16x16x32_bf16(wf[kk], xf[nt][kk], acc[nt], 0, 0, 0);
    float4 b4 = *(const float4*)(qkv_b + wt * 16 + g * 4);
    if (wt < 16) {           // q (wt<8, cols 0-127) and k (cols 128-255): col = wt*16+g*4
      float sc = wt < 8 ? 0.17677669529663687f : 1.0f;
      #pragma unroll
      for (int nt = 0; nt < 4; ++nt)
        st4(&s_qk[(nt * 16 + l) * 264 + wt * 16 + g * 4],
            (acc[nt][0] + b4.x) * sc, (acc[nt][1] + b4.y) * sc,
            (acc[nt][2] + b4.z) * sc, (acc[nt][3] + b4.w) * sc);
    } else {                 // v -> v^T [d][token]
      int d0 = wt * 16 - 256 + g * 4;
      #pragma unroll
      for (int nt = 0; nt < 4; ++nt) {
        s_vT[(d0 + 0) * 72 + nt * 16 + l] = f2bf(acc[nt][0] + b4.x);
        s_vT[(d0 + 1) * 72 + nt * 16 + l] = f2bf(acc[nt][1] + b4.y);
        s_vT[(d0 + 2) * 72 + nt * 16 + l] = f2bf(acc[nt][2] + b4.z);
        s_vT[(d0 + 3) * 72 + nt * 16 + l] = f2bf(acc[nt][3] + b4.w);
      }
    }
  }
  __syncthreads();

  // ---- phase 2: S^T = K.Q^T, table C-init; in-reg softmax; P [qtok][ktok] ----
  int h = wave >> 1, qh = wave & 1;          // head, qtok-half
  bf16x8 kf[4], qf[2];
  #pragma unroll
  for (int mt = 0; mt < 4; ++mt)
    kf[mt] = *(const bf16x8*)&s_qk[(mt * 16 + l) * 264 + 128 + h * 32 + g * 8];
  #pragma unroll
  for (int nt2 = 0; nt2 < 2; ++nt2) {
    int nt = qh * 2 + nt2;
    qf[nt2] = *(const bf16x8*)&s_qk[(nt * 16 + l) * 264 + h * 32 + g * 8];
  }
  __syncthreads();   // all q/k fragment reads done; s_qk reusable as P

  int clsid = ((wi == 7) ? 2 : 0) | ((wj == 7) ? 1 : 0);
  const float* tb = tbl + ((clsid * 4 + h) << 12);
  f32x4 sc[4][2];    // [mt=ktok tile][nt2=qtok tile half]
  #pragma unroll
  for (int nt2 = 0; nt2 < 2; ++nt2) {
    int nt = qh * 2 + nt2;
    #pragma unroll
    for (int mt = 0; mt < 4; ++mt) {
      f32x4 ci = *(const f32x4*)(tb + (nt * 16 + l) * 64 + mt * 16 + g * 4);
      sc[mt][nt2] = __builtin_amdgcn_mfma_f32_16x16x32_bf16(kf[mt], qf[nt2], ci, 0, 0, 0);
    }
  }

  #pragma unroll
  for (int nt2 = 0; nt2 < 2; ++nt2) {
    int nt = qh * 2 + nt2;
    float m = sc[0][nt2][0];
    #pragma unroll
    for (int mt = 0; mt < 4; ++mt)
      #pragma unroll
      for (int rr = 0; rr < 4; ++rr) m = fmaxf(m, sc[mt][nt2][rr]);
    m = fmaxf(m, __shfl_xor(m, 16));
    m = fmaxf(m, __shfl_xor(m, 32));
    float ssum = 0.f;
    #pragma unroll
    for (int mt = 0; mt < 4; ++mt)
      #pragma unroll
      for (int rr = 0; rr < 4; ++rr) {
        float e = __expf(sc[mt][nt2][rr] - m);
        sc[mt][nt2][rr] = e;
        ssum += e;
      }
    ssum += __shfl_xor(ssum, 16);
    ssum += __shfl_xor(ssum, 32);
    float inv = 1.0f / ssum;
    #pragma unroll
    for (int mt = 0; mt < 4; ++mt)
      st4(&s_qk[(nt * 16 + l) * 264 + h * 64 + mt * 16 + g * 4],
          sc[mt][nt2][0] * inv, sc[mt][nt2][1] * inv, sc[mt][nt2][2] * inv, sc[mt][nt2][3] * inv);
  }
  __syncthreads();   // P is cross-wave now (PV reads all 4 nt per head)

  // ---- phase 3: PV^T: A=v^T [d][ktok], B=P [qtok][ktok], D=[d][qtok] -> s_x[token][d] ----
  int dt = qh;       // d-subtile within head
  bf16x8 vf[2], pf[4][2];
  #pragma unroll
  for (int kk = 0; kk < 2; ++kk)
    vf[kk] = *(const bf16x8*)&s_vT[(h * 32 + dt * 16 + l) * 72 + kk * 32 + g * 8];
  #pragma unroll
  for (int nt = 0; nt < 4; ++nt)
    #pragma unroll
    for (int kk = 0; kk < 2; ++kk)
      pf[nt][kk] = *(const bf16x8*)&s_qk[(nt * 16 + l) * 264 + h * 64 + kk * 32 + g * 8];
  #pragma unroll
  for (int nt = 0; nt < 4; ++nt) {
    f32x4 a = (f32x4){0.f, 0.f, 0.f, 0.f};
    a = __builtin_amdgcn_mfma_f32_16x16x32_bf16(vf[0], pf[nt][0], a, 0, 0, 0);
    a = __builtin_amdgcn_mfma_f32_16x16x32_bf16(vf[1], pf[nt][1], a, 0, 0, 0);
    st4(&s_x[(nt * 16 + l) * 136 + h * 32 + dt * 16 + g * 4], a[0], a[1], a[2], a[3]);
  }
  __syncthreads();

  // ---- phase 4: proj^T: A=projW^T [pcol][d], B=PV [token][d], D=[pcol][token] ----
  unsigned short* stage = s_vT;   // 64x136 fits in 128x72 region
  bf16x8 of[4][4];
  #pragma unroll
  for (int nt = 0; nt < 4; ++nt)
    #pragma unroll
    for (int kk = 0; kk < 4; ++kk)
      of[nt][kk] = *(const bf16x8*)&s_x[(nt * 16 + l) * 136 + kk * 32 + g * 8];
  {
    int wt = wave;               // 0..7 covers 128 pcols
    bf16x8 wf[4];
    #pragma unroll
    for (int kk = 0; kk < 4; ++kk)
      wf[kk] = *(const bf16x8*)(projwT + (size_t)(wt * 16 + l) * DIM + kk * 32 + g * 8);
    f32x4 acc[4];
    #pragma unroll
    for (int nt = 0; nt < 4; ++nt) acc[nt] = (f32x4){0.f, 0.f, 0.f, 0.f};
    #pragma unroll
    for (int kk = 0; kk < 4; ++kk)
      #pragma unroll
      for (int nt = 0; nt < 4; ++nt)
        acc[nt] = __builtin_amdgcn_mfma_f32_16x16x32_bf16(wf[kk], of[nt][kk], acc[nt], 0, 0, 0);
    float4 b4 = *(const float4*)(proj_b + wt * 16 + g * 4);
    #pragma unroll
    for (int nt = 0; nt < 4; ++nt)
      st4(&stage[(nt * 16 + l) * 136 + wt * 16 + g * 4],
          acc[nt][0] + b4.x, acc[nt][1] + b4.y, acc[nt][2] + b4.z, acc[nt][3] + b4.w);
  }
  __syncthreads();

  unsigned short* outp = attn_out + (size_t)win * (NTOK * DIM);
  for (int idx = tid; idx < NTOK * 16; idx += 512) {
    int row = idx >> 4, seg = idx & 15;
    *(uint4*)(outp + idx * 8) = *(const uint4*)&stage[row * 136 + seg * 8];
  }
}

// gelu via sigmoid form: 0.5x(1+tanh(y)) = x * sigmoid(2y), y = 0.79788456(x+0.044715x^3)
__device__ __forceinline__ float gelu_f(float x) {
  float x2 = x * x;
  float t = x * __builtin_fmaf(x2, -0.10294429f, -2.3022077f);
  float e = __builtin_amdgcn_exp2f(t);
  return x * __builtin_amdgcn_rcpf(1.0f + e);
}

// ---------------- fused residual+LN2+MLP, 8 waves (512 thr) ----------------
// io = z + gelu(ln2(z)@w1+b1)@w2 + b2, z = x + attn(gathered), z in REGISTERS.
// Round-6 lesson: __launch_bounds__(512,4) capped VGPR at 64 (8 waves/SIMD)
// -> massive scratch spill (FETCH 79->221MB, WRITE 100->370MB). (512,2) lifts
// the cap to 128 (per-thread need ~95-110, no spill) with the same 16
// resident waves/CU as the 4-wave version (2 blocks x 8 waves).
__global__ __launch_bounds__(512, 2) void k_mlp(
    const float* __restrict__ x, const unsigned short* __restrict__ attn,
    const float* __restrict__ n2w, const float* __restrict__ n2b,
    const unsigned short* __restrict__ w1T, const float* __restrict__ b1,
    const unsigned short* __restrict__ w2T, const float* __restrict__ b2,
    float* __restrict__ io)
{
  __shared__ __align__(16) unsigned short s_t[2][64 * 136];
  __shared__ float s_part[64][8][2];
  int tid = threadIdx.x;
  int wave = tid >> 6;          // 0..7
  int lane = tid & 63;
  int l = lane & 15, g = lane >> 4;
  size_t m0 = (size_t)blockIdx.x * 64;
  int col0 = wave * 16 + g * 4;

  // ---- prologue: residual + LN2 ----
  float4 xz[4];
  float sA[4], sQ[4];
  #pragma unroll
  for (int nt = 0; nt < 4; ++nt) {
    int row = nt * 16 + l;
    int t = (int)m0 + row;
    int bi = t / (HH * WW2);
    int r = t % (HH * WW2);
    int i = r / WW2, j = r % WW2;
    int si = i >= SHIFT ? i - SHIFT : i + (HH - SHIFT);
    int sj = j >= SHIFT ? j - SHIFT : j + (WW2 - SHIFT);
    int win = bi * NWIN + (si / WS) * 8 + (sj / WS);
    int tok = (si % WS) * WS + (sj % WS);
    float4 xv = *(const float4*)(x + (size_t)t * DIM + col0);
    ushort4 av = *(const ushort4*)(attn + ((size_t)(win * NTOK + tok)) * DIM + col0);
    float4 z;
    z.x = xv.x + __uint_as_float((unsigned)av.x << 16);
    z.y = xv.y + __uint_as_float((unsigned)av.y << 16);
    z.z = xv.z + __uint_as_float((unsigned)av.z << 16);
    z.w = xv.w + __uint_as_float((unsigned)av.w << 16);
    xz[nt] = z;
    float s = z.x + z.y + z.z + z.w;
    float sq = z.x * z.x + z.y * z.y + z.z * z.z + z.w * z.w;
    s += __shfl_xor(s, 16); s += __shfl_xor(s, 32);
    sq += __shfl_xor(sq, 16); sq += __shfl_xor(sq, 32);
    sA[nt] = s; sQ[nt] = sq;   // per-row partial over this wave's 16 cols
  }
  if (g == 0) {
    #pragma unroll
    for (int nt = 0; nt < 4; ++nt) {
      s_part[nt * 16 + l][wave][0] = sA[nt];
      s_part[nt * 16 + l][wave][1] = sQ[nt];
    }
  }
  __syncthreads();
  float4 wv0 = *(const float4*)(n2w + col0);
  float4 bv0 = *(const float4*)(n2b + col0);
  #pragma unroll
  for (int nt = 0; nt < 4; ++nt) {
    int row = nt * 16 + l;
    float s = 0.f, sq = 0.f;
    #pragma unroll
    for (int wv = 0; wv < 8; ++wv) { s += s_part[row][wv][0]; sq += s_part[row][wv][1]; }
    float mean = s * (1.0f / DIM);
    float var = sq * (1.0f / DIM) - mean * mean;
    float rs = rsqrtf(var + 1e-5f);
    float4 z0 = xz[nt];
    st4(&s_t[1][row * 136 + col0],
        (z0.x - mean) * rs * wv0.x + bv0.x, (z0.y - mean) * rs * wv0.y + bv0.y,
        (z0.z - mean) * rs * wv0.z + bv0.z, (z0.w - mean) * rs * wv0.w + bv0.w);
  }
  __syncthreads();

  bf16x8 hf[4][4];
  #pragma unroll
  for (int nt = 0; nt < 4; ++nt)
    #pragma unroll
    for (int kk = 0; kk < 4; ++kk)
      hf[nt][kk] = *(const bf16x8*)&s_t[1][(nt * 16 + l) * 136 + kk * 32 + g * 8];

  f32x4 o[4];
  #pragma unroll
  for (int nt = 0; nt < 4; ++nt) o[nt] = (f32x4){0.f, 0.f, 0.f, 0.f};

  // Double-buffered s_t (first write into s_t[1] at c=1 is fenced by
  // barrier(0); buffer p rewritten at c+2 is fenced by barrier(c+1) which no
  // wave passes before its GEMM2(c) reads).
  for (int c = 0; c < 4; ++c) {
    unsigned short* buf = s_t[c & 1];
    // GEMM1^T chunk: wave's 16 w1cols; D[w1col][token], gelu, store buf
    {
      int n0 = c * 128 + wave * 16;
      bf16x8 wf[4];
      #pragma unroll
      for (int kk = 0; kk < 4; ++kk)
        wf[kk] = *(const bf16x8*)(w1T + (size_t)(n0 + l) * DIM + kk * 32 + g * 8);
      f32x4 acc[4];
      #pragma unroll
      for (int nt = 0; nt < 4; ++nt) acc[nt] = (f32x4){0.f, 0.f, 0.f, 0.f};
      #pragma unroll
      for (int kk = 0; kk < 4; ++kk)
        #pragma unroll
        for (int nt = 0; nt < 4; ++nt)
          acc[nt] = __builtin_amdgcn_mfma_f32_16x16x32_bf16(wf[kk], hf[nt][kk], acc[nt], 0, 0, 0);
      float4 b4 = *(const float4*)(b1 + n0 + g * 4);
      #pragma unroll
      for (int nt = 0; nt < 4; ++nt)
        st4(&buf[(nt * 16 + l) * 136 + wave * 16 + g * 4],
            gelu_f(acc[nt][0] + b4.x), gelu_f(acc[nt][1] + b4.y),
            gelu_f(acc[nt][2] + b4.z), gelu_f(acc[nt][3] + b4.w));
    }
    __syncthreads();
    // GEMM2^T chunk: o[pcol=wave tile][token] += w2 chunk . t chunk
    #pragma unroll
    for (int kk = 0; kk < 4; ++kk) {
      bf16x8 tf[4];
      #pragma unroll
      for (int nt = 0; nt < 4; ++nt)
        tf[nt] = *(const bf16x8*)&buf[(nt * 16 + l) * 136 + kk * 32 + g * 8];
      bf16x8 wf2 = *(const bf16x8*)(w2T + (size_t)(wave * 16 + l) * 512 + c * 128 + kk * 32 + g * 8);
      #pragma unroll
      for (int nt = 0; nt < 4; ++nt)
        o[nt] = __builtin_amdgcn_mfma_f32_16x16x32_bf16(wf2, tf[nt], o[nt], 0, 0, 0);
    }
  }

  // ---- epilogue: io = z + mlp_out + b2, single store, no load ----
  {
    float4 b4 = *(const float4*)(b2 + col0);
    #pragma unroll
    for (int nt = 0; nt < 4; ++nt) {
      float4 z = xz[nt];
      float4 pv;
      pv.x = z.x + o[nt][0] + b4.x;
      pv.y = z.y + o[nt][1] + b4.y;
      pv.z = z.z + o[nt][2] + b4.z;
      pv.w = z.w + o[nt][3] + b4.w;
      *(float4*)(io + (m0 + nt * 16 + l) * DIM + col0) = pv;
    }
  }
}

extern "C" void kernel_launch(void* const* d_in, const int* in_sizes, int n_in,
                              void* d_out, int out_size, void* d_ws, size_t ws_size,
                              hipStream_t stream) {
  const float* x       = (const float*)d_in[0];
  const float* qkv_w   = (const float*)d_in[1];
  const float* qkv_b   = (const float*)d_in[2];
  const float* proj_w  = (const float*)d_in[3];
  const float* proj_b  = (const float*)d_in[4];
  const float* rpb     = (const float*)d_in[5];
  const float* n1w     = (const float*)d_in[6];
  const float* n1b     = (const float*)d_in[7];
  const float* n2w     = (const float*)d_in[8];
  const float* n2b     = (const float*)d_in[9];
  const float* mlp_w1  = (const float*)d_in[10];
  const float* mlp_b1  = (const float*)d_in[11];
  const float* mlp_w2  = (const float*)d_in[12];
  const float* mlp_b2  = (const float*)d_in[13];
  float* out = (float*)d_out;

  char* ws = (char*)d_ws;
  const size_t TOKB = (size_t)TOKENS * DIM * 2;     // 51,380,224 B
  unsigned short* attn_o = (unsigned short*)(ws);
  unsigned short* qkvwT  = (unsigned short*)(ws + TOKB);
  unsigned short* projwT = (unsigned short*)(ws + TOKB + 98304);
  unsigned short* w1T    = (unsigned short*)(ws + TOKB + 98304 + 32768);
  unsigned short* w2T    = (unsigned short*)(ws + TOKB + 98304 + 32768 + 131072);
  float*          tbl    = (float*)(ws + TOKB + 98304 + 32768 + 131072 + 131072);  // 262144 B

  k_prep<<<768, 256, 0, stream>>>(qkv_w, proj_w, mlp_w1, mlp_w2, qkvwT, projwT, w1T, w2T);
  k_tbl<<<256, 256, 0, stream>>>(rpb, tbl);
  k_attn<<<WINDOWS, 512, 0, stream>>>(x, n1w, n1b, qkvwT, qkv_b, projwT, proj_b, tbl, attn_o);
  k_mlp<<<TOKENS / 64, 512, 0, stream>>>(x, attn_o, n2w, n2b, w1T, mlp_b1, w2T, mlp_b2, out);
}

// Round 8
// 442.475 us; speedup vs baseline: 1.1190x; 1.0733x over previous
//
#include <hip/hip_runtime.h>

#define HH 56
#define WW2 56
#define WS 7
#define SHIFT 3
#define HEADS 4
#define DIM 128
#define NTOK 49
#define BATCH 64
#define TOKENS (BATCH*HH*WW2)   // 200704
#define NWIN 64                 // windows per image (8x8)
#define WINDOWS (BATCH*NWIN)    // 4096

typedef __bf16 bf16x8 __attribute__((ext_vector_type(8)));
typedef float  f32x4  __attribute__((ext_vector_type(4)));

// Native RTNE f32->bf16 (lowers to v_cvt_pk_bf16_f32 on gfx950).
__device__ __forceinline__ unsigned short f2bf(float f) {
  union { __bf16 b; unsigned short u; } cv;
  cv.b = (__bf16)f;
  return cv.u;
}

__device__ __forceinline__ void st4(unsigned short* p, float a, float b, float c, float d) {
  ushort4 pk; pk.x = f2bf(a); pk.y = f2bf(b); pk.z = f2bf(c); pk.w = f2bf(d);
  *(ushort4*)p = pk;
}

__device__ __forceinline__ int reg3(int g) { return g >= 53 ? 2 : (g >= 49 ? 1 : 0); }

// ---------------- weight prep: transpose + bf16 ----------------
__global__ __launch_bounds__(256) void k_prep(
    const float* __restrict__ qkv_w, const float* __restrict__ proj_w,
    const float* __restrict__ w1, const float* __restrict__ w2,
    unsigned short* __restrict__ qkvwT, unsigned short* __restrict__ projwT,
    unsigned short* __restrict__ w1T, unsigned short* __restrict__ w2T)
{
  int idx = blockIdx.x * 256 + threadIdx.x;
  if (idx < 49152) {                       // qkv_w [128][384] -> qkvwT [384][128]
    int n = idx >> 7, k = idx & 127;
    qkvwT[idx] = f2bf(qkv_w[k * 384 + n]);
  } else if (idx < 65536) {                // proj_w [128][128] -> projwT [128][128]
    int i = idx - 49152; int n = i >> 7, k = i & 127;
    projwT[i] = f2bf(proj_w[k * 128 + n]);
  } else if (idx < 131072) {               // mlp_w1 [128][512] -> w1T [512][128]
    int i = idx - 65536; int n = i >> 7, k = i & 127;
    w1T[i] = f2bf(w1[k * 512 + n]);
  } else {                                 // mlp_w2 [512][128] -> w2T [128][512]
    int i = idx - 131072; int n = i >> 9, k = i & 511;
    w2T[i] = f2bf(w2[k * 128 + n]);
  }
}

// ---------------- bias+mask table: [cls][head][qtoken 64][ktoken 64] fp32 ----------------
__global__ __launch_bounds__(256) void k_tbl(const float* __restrict__ rpb, float* __restrict__ tbl)
{
  int idx = blockIdx.x * 256 + threadIdx.x;   // 65536 entries
  int kt = idx & 63, qt = (idx >> 6) & 63, h = (idx >> 12) & 3, cls = idx >> 14;
  float v;
  if (qt >= NTOK || kt >= NTOK) v = -3e38f;
  else {
    int qi = qt / 7, qj = qt % 7, ki = kt / 7, kj = kt % 7;
    int bi = (cls & 2) ? 49 : 0, bj = (cls & 1) ? 49 : 0;
    int rq = reg3(bi + qi) * 3 + reg3(bj + qj);
    int rk = reg3(bi + ki) * 3 + reg3(bj + kj);
    v = rpb[((qi - ki + 6) * 13 + (qj - kj + 6)) * HEADS + h] + (rq != rk ? -100.0f : 0.0f);
  }
  tbl[idx] = v;
}

// ---------------- fused LN1 + window attention, 8 waves (512 thr) ----------------
// __launch_bounds__(512, 2): empirically (rounds 6/7) the 2nd arg at 512
// threads acts as blocks/CU — (512,4) caps VGPR at 64 and forces scratch
// spill (phase 1 alone holds xf[4][4] = 64 VGPRs). LDS (69.6 KB) already
// limits residency to 2 blocks/CU, so (512,2) lifts the cap to 128 with
// zero occupancy cost.
__global__ __launch_bounds__(512, 2) void k_attn(
    const float* __restrict__ x,
    const float* __restrict__ n1w, const float* __restrict__ n1b,
    const unsigned short* __restrict__ qkvwT,
    const float* __restrict__ qkv_b,
    const unsigned short* __restrict__ projwT,
    const float* __restrict__ proj_b,
    const float* __restrict__ tbl,
    unsigned short* __restrict__ attn_out)
{
  __shared__ __align__(16) unsigned short s_x[64 * 136];   // x tile; then PV [token][d]
  __shared__ __align__(16) unsigned short s_qk[64 * 264];  // q|k [token][dim]; then P [qtok][ktok] per head
  __shared__ __align__(16) unsigned short s_vT[128 * 72];  // v^T [d][token]; then proj-out stage

  int tid = threadIdx.x;
  int wave = tid >> 6;          // 0..7
  int lane = tid & 63;
  int l = lane & 15, g = lane >> 4;
  int win = blockIdx.x;
  int wi = (win & 63) >> 3, wj = win & 7;
  int bi = win >> 6;

  // ---- phase 0: gather shifted rows of x, LN1 -> bf16 s_x; zero pad rows ----
  {
    float2 wv1 = *(const float2*)(n1w + lane * 2);
    float2 bv1 = *(const float2*)(n1b + lane * 2);
    float2 vr[7];
    #pragma unroll
    for (int rr = 0; rr < 7; ++rr) {       // issue all row loads up front
      int row = wave + rr * 8;
      if (row < NTOK) {
        int ti = row / 7, tj = row % 7;
        int i = wi * WS + ti + SHIFT; if (i >= HH) i -= HH;
        int j = wj * WS + tj + SHIFT; if (j >= WW2) j -= WW2;
        const float* xp = x + ((size_t)(bi * (HH * WW2) + i * WW2 + j)) * DIM;
        vr[rr] = *(const float2*)(xp + lane * 2);
      }
    }
    #pragma unroll
    for (int rr = 0; rr < 7; ++rr) {
      int row = wave + rr * 8;
      if (row < NTOK) {
        float2 v = vr[rr];
        float s = v.x + v.y, sq = v.x * v.x + v.y * v.y;
        #pragma unroll
        for (int off = 32; off; off >>= 1) {
          s += __shfl_xor(s, off);
          sq += __shfl_xor(sq, off);
        }
        float mean = s * (1.0f / DIM);
        float var = sq * (1.0f / DIM) - mean * mean;
        float rs = rsqrtf(var + 1e-5f);
        float y0 = (v.x - mean) * rs * wv1.x + bv1.x;
        float y1 = (v.y - mean) * rs * wv1.y + bv1.y;
        unsigned pack = ((unsigned)f2bf(y1) << 16) | (unsigned)f2bf(y0);
        *(unsigned*)&s_x[row * 136 + lane * 2] = pack;
      }
    }
  }
  for (int idx = tid; idx < 15 * 17; idx += 512) {
    int row = 49 + idx / 17, seg = idx % 17;
    *(uint4*)&s_x[row * 136 + seg * 8] = make_uint4(0, 0, 0, 0);
  }
  __syncthreads();

  // ---- phase 1: QKV^T GEMM: A=weights [wcol][k], B=x [token][k], D=[wcol][token] ----
  bf16x8 xf[4][4];   // [nt(token tile)][kk]
  #pragma unroll
  for (int nt = 0; nt < 4; ++nt)
    #pragma unroll
    for (int kk = 0; kk < 4; ++kk)
      xf[nt][kk] = *(const bf16x8*)&s_x[(nt * 16 + l) * 136 + kk * 32 + g * 8];

  #pragma unroll
  for (int wti = 0; wti < 3; ++wti) {
    int wt = wave * 3 + wti;                 // m-tile over 384 wcols, 0..23
    bf16x8 wf[4];
    #pragma unroll
    for (int kk = 0; kk < 4; ++kk)
      wf[kk] = *(const bf16x8*)(qkvwT + (size_t)(wt * 16 + l) * DIM + kk * 32 + g * 8);
    f32x4 acc[4];
    #pragma unroll
    for (int nt = 0; nt < 4; ++nt) acc[nt] = (f32x4){0.f, 0.f, 0.f, 0.f};
    #pragma unroll
    for (int kk = 0; kk < 4; ++kk)
      #pragma unroll
      for (int nt = 0; nt < 4; ++nt)
        acc[nt] = __builtin_amdgcn_mfma_f32_16x16x32_bf16(wf[kk], xf[nt][kk], acc[nt], 0, 0, 0);
    float4 b4 = *(const float4*)(qkv_b + wt * 16 + g * 4);
    if (wt < 16) {           // q (wt<8, cols 0-127) and k (cols 128-255): col = wt*16+g*4
      float sc = wt < 8 ? 0.17677669529663687f : 1.0f;
      #pragma unroll
      for (int nt = 0; nt < 4; ++nt)
        st4(&s_qk[(nt * 16 + l) * 264 + wt * 16 + g * 4],
            (acc[nt][0] + b4.x) * sc, (acc[nt][1] + b4.y) * sc,
            (acc[nt][2] + b4.z) * sc, (acc[nt][3] + b4.w) * sc);
    } else {                 // v -> v^T [d][token]
      int d0 = wt * 16 - 256 + g * 4;
      #pragma unroll
      for (int nt = 0; nt < 4; ++nt) {
        s_vT[(d0 + 0) * 72 + nt * 16 + l] = f2bf(acc[nt][0] + b4.x);
        s_vT[(d0 + 1) * 72 + nt * 16 + l] = f2bf(acc[nt][1] + b4.y);
        s_vT[(d0 + 2) * 72 + nt * 16 + l] = f2bf(acc[nt][2] + b4.z);
        s_vT[(d0 + 3) * 72 + nt * 16 + l] = f2bf(acc[nt][3] + b4.w);
      }
    }
  }
  __syncthreads();

  // ---- phase 2: S^T = K.Q^T, table C-init; in-reg softmax; P [qtok][ktok] ----
  int h = wave >> 1, qh = wave & 1;          // head, qtok-half
  bf16x8 kf[4], qf[2];
  #pragma unroll
  for (int mt = 0; mt < 4; ++mt)
    kf[mt] = *(const bf16x8*)&s_qk[(mt * 16 + l) * 264 + 128 + h * 32 + g * 8];
  #pragma unroll
  for (int nt2 = 0; nt2 < 2; ++nt2) {
    int nt = qh * 2 + nt2;
    qf[nt2] = *(const bf16x8*)&s_qk[(nt * 16 + l) * 264 + h * 32 + g * 8];
  }
  __syncthreads();   // all q/k fragment reads done; s_qk reusable as P

  int clsid = ((wi == 7) ? 2 : 0) | ((wj == 7) ? 1 : 0);
  const float* tb = tbl + ((clsid * 4 + h) << 12);
  f32x4 sc[4][2];    // [mt=ktok tile][nt2=qtok tile half]
  #pragma unroll
  for (int nt2 = 0; nt2 < 2; ++nt2) {
    int nt = qh * 2 + nt2;
    #pragma unroll
    for (int mt = 0; mt < 4; ++mt) {
      f32x4 ci = *(const f32x4*)(tb + (nt * 16 + l) * 64 + mt * 16 + g * 4);
      sc[mt][nt2] = __builtin_amdgcn_mfma_f32_16x16x32_bf16(kf[mt], qf[nt2], ci, 0, 0, 0);
    }
  }

  #pragma unroll
  for (int nt2 = 0; nt2 < 2; ++nt2) {
    int nt = qh * 2 + nt2;
    float m = sc[0][nt2][0];
    #pragma unroll
    for (int mt = 0; mt < 4; ++mt)
      #pragma unroll
      for (int rr = 0; rr < 4; ++rr) m = fmaxf(m, sc[mt][nt2][rr]);
    m = fmaxf(m, __shfl_xor(m, 16));
    m = fmaxf(m, __shfl_xor(m, 32));
    float ssum = 0.f;
    #pragma unroll
    for (int mt = 0; mt < 4; ++mt)
      #pragma unroll
      for (int rr = 0; rr < 4; ++rr) {
        float e = __expf(sc[mt][nt2][rr] - m);
        sc[mt][nt2][rr] = e;
        ssum += e;
      }
    ssum += __shfl_xor(ssum, 16);
    ssum += __shfl_xor(ssum, 32);
    float inv = 1.0f / ssum;
    #pragma unroll
    for (int mt = 0; mt < 4; ++mt)
      st4(&s_qk[(nt * 16 + l) * 264 + h * 64 + mt * 16 + g * 4],
          sc[mt][nt2][0] * inv, sc[mt][nt2][1] * inv, sc[mt][nt2][2] * inv, sc[mt][nt2][3] * inv);
  }
  __syncthreads();   // P is cross-wave now (PV reads all 4 nt per head)

  // ---- phase 3: PV^T: A=v^T [d][ktok], B=P [qtok][ktok], D=[d][qtok] -> s_x[token][d] ----
  int dt = qh;       // d-subtile within head
  bf16x8 vf[2], pf[4][2];
  #pragma unroll
  for (int kk = 0; kk < 2; ++kk)
    vf[kk] = *(const bf16x8*)&s_vT[(h * 32 + dt * 16 + l) * 72 + kk * 32 + g * 8];
  #pragma unroll
  for (int nt = 0; nt < 4; ++nt)
    #pragma unroll
    for (int kk = 0; kk < 2; ++kk)
      pf[nt][kk] = *(const bf16x8*)&s_qk[(nt * 16 + l) * 264 + h * 64 + kk * 32 + g * 8];
  #pragma unroll
  for (int nt = 0; nt < 4; ++nt) {
    f32x4 a = (f32x4){0.f, 0.f, 0.f, 0.f};
    a = __builtin_amdgcn_mfma_f32_16x16x32_bf16(vf[0], pf[nt][0], a, 0, 0, 0);
    a = __builtin_amdgcn_mfma_f32_16x16x32_bf16(vf[1], pf[nt][1], a, 0, 0, 0);
    st4(&s_x[(nt * 16 + l) * 136 + h * 32 + dt * 16 + g * 4], a[0], a[1], a[2], a[3]);
  }
  __syncthreads();

  // ---- phase 4: proj^T: A=projW^T [pcol][d], B=PV [token][d], D=[pcol][token] ----
  unsigned short* stage = s_vT;   // 64x136 fits in 128x72 region
  bf16x8 of[4][4];
  #pragma unroll
  for (int nt = 0; nt < 4; ++nt)
    #pragma unroll
    for (int kk = 0; kk < 4; ++kk)
      of[nt][kk] = *(const bf16x8*)&s_x[(nt * 16 + l) * 136 + kk * 32 + g * 8];
  {
    int wt = wave;               // 0..7 covers 128 pcols
    bf16x8 wf[4];
    #pragma unroll
    for (int kk = 0; kk < 4; ++kk)
      wf[kk] = *(const bf16x8*)(projwT + (size_t)(wt * 16 + l) * DIM + kk * 32 + g * 8);
    f32x4 acc[4];
    #pragma unroll
    for (int nt = 0; nt < 4; ++nt) acc[nt] = (f32x4){0.f, 0.f, 0.f, 0.f};
    #pragma unroll
    for (int kk = 0; kk < 4; ++kk)
      #pragma unroll
      for (int nt = 0; nt < 4; ++nt)
        acc[nt] = __builtin_amdgcn_mfma_f32_16x16x32_bf16(wf[kk], of[nt][kk], acc[nt], 0, 0, 0);
    float4 b4 = *(const float4*)(proj_b + wt * 16 + g * 4);
    #pragma unroll
    for (int nt = 0; nt < 4; ++nt)
      st4(&stage[(nt * 16 + l) * 136 + wt * 16 + g * 4],
          acc[nt][0] + b4.x, acc[nt][1] + b4.y, acc[nt][2] + b4.z, acc[nt][3] + b4.w);
  }
  __syncthreads();

  unsigned short* outp = attn_out + (size_t)win * (NTOK * DIM);
  for (int idx = tid; idx < NTOK * 16; idx += 512) {
    int row = idx >> 4, seg = idx & 15;
    *(uint4*)(outp + idx * 8) = *(const uint4*)&stage[row * 136 + seg * 8];
  }
}

// gelu via sigmoid form: 0.5x(1+tanh(y)) = x * sigmoid(2y), y = 0.79788456(x+0.044715x^3)
__device__ __forceinline__ float gelu_f(float x) {
  float x2 = x * x;
  float t = x * __builtin_fmaf(x2, -0.10294429f, -2.3022077f);
  float e = __builtin_amdgcn_exp2f(t);
  return x * __builtin_amdgcn_rcpf(1.0f + e);
}

// ---------------- fused residual+LN2+MLP, 4 waves (256 thr) ----------------
// REVERTED to the round-5 version (measured 171.5 µs): the 8-wave split
// (rounds 6/7) doubled LDS traffic per MFMA and bank conflicts (6.6M->15.5M)
// and was 211-235 µs even without spill. Each thread owns the SAME (row,col)
// fragments in prologue and epilogue (row = nt*16+l, col = wave*32+wti*16+g*4).
// z stays in registers; io is written exactly once.
__global__ __launch_bounds__(256) void k_mlp(
    const float* __restrict__ x, const unsigned short* __restrict__ attn,
    const float* __restrict__ n2w, const float* __restrict__ n2b,
    const unsigned short* __restrict__ w1T, const float* __restrict__ b1,
    const unsigned short* __restrict__ w2T, const float* __restrict__ b2,
    float* __restrict__ io)
{
  __shared__ __align__(16) unsigned short s_t[2][64 * 136];
  __shared__ float s_part[64][4][2];
  int tid = threadIdx.x;
  int wave = tid >> 6;
  int lane = tid & 63;
  int l = lane & 15, g = lane >> 4;
  size_t m0 = (size_t)blockIdx.x * 64;
  int col0 = wave * 32 + g * 4;        // wti=0 col; wti=1 col = col0+16

  // ---- prologue: residual + LN2 ----
  float4 xz[4][2];
  float sA[4], sQ[4];
  #pragma unroll
  for (int nt = 0; nt < 4; ++nt) {
    int row = nt * 16 + l;
    int t = (int)m0 + row;
    int bi = t / (HH * WW2);
    int r = t % (HH * WW2);
    int i = r / WW2, j = r % WW2;
    int si = i >= SHIFT ? i - SHIFT : i + (HH - SHIFT);
    int sj = j >= SHIFT ? j - SHIFT : j + (WW2 - SHIFT);
    int win = bi * NWIN + (si / WS) * 8 + (sj / WS);
    int tok = (si % WS) * WS + (sj % WS);
    const float* xp = x + (size_t)t * DIM;
    const unsigned short* ap = attn + ((size_t)(win * NTOK + tok)) * DIM;
    float s = 0.f, sq = 0.f;
    #pragma unroll
    for (int wti = 0; wti < 2; ++wti) {
      int col = col0 + wti * 16;
      float4 xv = *(const float4*)(xp + col);
      ushort4 av = *(const ushort4*)(ap + col);
      float4 z;
      z.x = xv.x + __uint_as_float((unsigned)av.x << 16);
      z.y = xv.y + __uint_as_float((unsigned)av.y << 16);
      z.z = xv.z + __uint_as_float((unsigned)av.z << 16);
      z.w = xv.w + __uint_as_float((unsigned)av.w << 16);
      xz[nt][wti] = z;
      s += z.x + z.y + z.z + z.w;
      sq += z.x * z.x + z.y * z.y + z.z * z.z + z.w * z.w;
    }
    s += __shfl_xor(s, 16); s += __shfl_xor(s, 32);
    sq += __shfl_xor(sq, 16); sq += __shfl_xor(sq, 32);
    sA[nt] = s; sQ[nt] = sq;   // per-row partial over this wave's 32 cols
  }
  if (g == 0) {
    #pragma unroll
    for (int nt = 0; nt < 4; ++nt) {
      s_part[nt * 16 + l][wave][0] = sA[nt];
      s_part[nt * 16 + l][wave][1] = sQ[nt];
    }
  }
  __syncthreads();
  float4 wv0 = *(const float4*)(n2w + col0);
  float4 wv1 = *(const float4*)(n2w + col0 + 16);
  float4 bv0 = *(const float4*)(n2b + col0);
  float4 bv1 = *(const float4*)(n2b + col0 + 16);
  #pragma unroll
  for (int nt = 0; nt < 4; ++nt) {
    int row = nt * 16 + l;
    float s = 0.f, sq = 0.f;
    #pragma unroll
    for (int wv = 0; wv < 4; ++wv) { s += s_part[row][wv][0]; sq += s_part[row][wv][1]; }
    float mean = s * (1.0f / DIM);
    float var = sq * (1.0f / DIM) - mean * mean;
    float rs = rsqrtf(var + 1e-5f);
    float4 z0 = xz[nt][0], z1 = xz[nt][1];
    st4(&s_t[1][row * 136 + col0],
        (z0.x - mean) * rs * wv0.x + bv0.x, (z0.y - mean) * rs * wv0.y + bv0.y,
        (z0.z - mean) * rs * wv0.z + bv0.z, (z0.w - mean) * rs * wv0.w + bv0.w);
    st4(&s_t[1][row * 136 + col0 + 16],
        (z1.x - mean) * rs * wv1.x + bv1.x, (z1.y - mean) * rs * wv1.y + bv1.y,
        (z1.z - mean) * rs * wv1.z + bv1.z, (z1.w - mean) * rs * wv1.w + bv1.w);
  }
  __syncthreads();

  bf16x8 hf[4][4];
  #pragma unroll
  for (int nt = 0; nt < 4; ++nt)
    #pragma unroll
    for (int kk = 0; kk < 4; ++kk)
      hf[nt][kk] = *(const bf16x8*)&s_t[1][(nt * 16 + l) * 136 + kk * 32 + g * 8];

  f32x4 o[2][4];
  #pragma unroll
  for (int wti = 0; wti < 2; ++wti)
    #pragma unroll
    for (int nt = 0; nt < 4; ++nt) o[wti][nt] = (f32x4){0.f, 0.f, 0.f, 0.f};

  // Double-buffered s_t: first write into s_t[1] happens at c=1, after the c=0
  // barrier; by then every wave has passed GEMM1(0), hence finished hf reads.
  // Writes to buffer p at chunk c+2 are fenced by barrier(c+1), which no wave
  // passes before completing GEMM2(c) reads of p.
  for (int c = 0; c < 4; ++c) {
    unsigned short* buf = s_t[c & 1];
    // GEMM1^T chunk: D[w1col][token], gelu, store buf[token][w1col-local]
    #pragma unroll
    for (int wti = 0; wti < 2; ++wti) {
      int wt = wave * 2 + wti;
      int n0 = c * 128 + wt * 16;
      bf16x8 wf[4];
      #pragma unroll
      for (int kk = 0; kk < 4; ++kk)
        wf[kk] = *(const bf16x8*)(w1T + (size_t)(n0 + l) * DIM + kk * 32 + g * 8);
      f32x4 acc[4];
      #pragma unroll
      for (int nt = 0; nt < 4; ++nt) acc[nt] = (f32x4){0.f, 0.f, 0.f, 0.f};
      #pragma unroll
      for (int kk = 0; kk < 4; ++kk)
        #pragma unroll
        for (int nt = 0; nt < 4; ++nt)
          acc[nt] = __builtin_amdgcn_mfma_f32_16x16x32_bf16(wf[kk], hf[nt][kk], acc[nt], 0, 0, 0);
      float4 b4 = *(const float4*)(b1 + n0 + g * 4);
      #pragma unroll
      for (int nt = 0; nt < 4; ++nt)
        st4(&buf[(nt * 16 + l) * 136 + wt * 16 + g * 4],
            gelu_f(acc[nt][0] + b4.x), gelu_f(acc[nt][1] + b4.y),
            gelu_f(acc[nt][2] + b4.z), gelu_f(acc[nt][3] + b4.w));
    }
    __syncthreads();
    // GEMM2^T chunk: o[pcol][token] += w2 chunk . t chunk  (reads buf; next
    // chunk's GEMM1 writes go to the other buffer, so no trailing barrier)
    #pragma unroll
    for (int kk = 0; kk < 4; ++kk) {
      bf16x8 tf[4];
      #pragma unroll
      for (int nt = 0; nt < 4; ++nt)
        tf[nt] = *(const bf16x8*)&buf[(nt * 16 + l) * 136 + kk * 32 + g * 8];
      #pragma unroll
      for (int wti = 0; wti < 2; ++wti) {
        int wt = wave * 2 + wti;
        bf16x8 wf2 = *(const bf16x8*)(w2T + (size_t)(wt * 16 + l) * 512 + c * 128 + kk * 32 + g * 8);
        #pragma unroll
        for (int nt = 0; nt < 4; ++nt)
          o[wti][nt] = __builtin_amdgcn_mfma_f32_16x16x32_bf16(wf2, tf[nt], o[wti][nt], 0, 0, 0);
      }
    }
  }

  // ---- epilogue: io = z + mlp_out + b2, single store, no load ----
  #pragma unroll
  for (int wti = 0; wti < 2; ++wti) {
    int wt = wave * 2 + wti;
    float4 b4 = *(const float4*)(b2 + wt * 16 + g * 4);
    #pragma unroll
    for (int nt = 0; nt < 4; ++nt) {
      float4 z = xz[nt][wti];
      float4 pv;
      pv.x = z.x + o[wti][nt][0] + b4.x;
      pv.y = z.y + o[wti][nt][1] + b4.y;
      pv.z = z.z + o[wti][nt][2] + b4.z;
      pv.w = z.w + o[wti][nt][3] + b4.w;
      *(float4*)(io + (m0 + nt * 16 + l) * DIM + wt * 16 + g * 4) = pv;
    }
  }
}

extern "C" void kernel_launch(void* const* d_in, const int* in_sizes, int n_in,
                              void* d_out, int out_size, void* d_ws, size_t ws_size,
                              hipStream_t stream) {
  const float* x       = (const float*)d_in[0];
  const float* qkv_w   = (const float*)d_in[1];
  const float* qkv_b   = (const float*)d_in[2];
  const float* proj_w  = (const float*)d_in[3];
  const float* proj_b  = (const float*)d_in[4];
  const float* rpb     = (const float*)d_in[5];
  const float* n1w     = (const float*)d_in[6];
  const float* n1b     = (const float*)d_in[7];
  const float* n2w     = (const float*)d_in[8];
  const float* n2b     = (const float*)d_in[9];
  const float* mlp_w1  = (const float*)d_in[10];
  const float* mlp_b1  = (const float*)d_in[11];
  const float* mlp_w2  = (const float*)d_in[12];
  const float* mlp_b2  = (const float*)d_in[13];
  float* out = (float*)d_out;

  char* ws = (char*)d_ws;
  const size_t TOKB = (size_t)TOKENS * DIM * 2;     // 51,380,224 B
  unsigned short* attn_o = (unsigned short*)(ws);
  unsigned short* qkvwT  = (unsigned short*)(ws + TOKB);
  unsigned short* projwT = (unsigned short*)(ws + TOKB + 98304);
  unsigned short* w1T    = (unsigned short*)(ws + TOKB + 98304 + 32768);
  unsigned short* w2T    = (unsigned short*)(ws + TOKB + 98304 + 32768 + 131072);
  float*          tbl    = (float*)(ws + TOKB + 98304 + 32768 + 131072 + 131072);  // 262144 B

  k_prep<<<768, 256, 0, stream>>>(qkv_w, proj_w, mlp_w1, mlp_w2, qkvwT, projwT, w1T, w2T);
  k_tbl<<<256, 256, 0, stream>>>(rpb, tbl);
  k_attn<<<WINDOWS, 512, 0, stream>>>(x, n1w, n1b, qkvwT, qkv_b, projwT, proj_b, tbl, attn_o);
  k_mlp<<<TOKENS / 64, 256, 0, stream>>>(x, attn_o, n2w, n2b, w1T, mlp_b1, w2T, mlp_b2, out);
}

// Round 9
// 424.639 us; speedup vs baseline: 1.1660x; 1.0420x over previous
//
#include <hip/hip_runtime.h>

#define HH 56
#define WW2 56
#define WS 7
#define SHIFT 3
#define HEADS 4
#define DIM 128
#define NTOK 49
#define BATCH 64
#define TOKENS (BATCH*HH*WW2)   // 200704
#define NWIN 64                 // windows per image (8x8)
#define WINDOWS (BATCH*NWIN)    // 4096

typedef __bf16 bf16x8 __attribute__((ext_vector_type(8)));
typedef float  f32x4  __attribute__((ext_vector_type(4)));

// Native RTNE f32->bf16 (lowers to v_cvt_pk_bf16_f32 on gfx950).
__device__ __forceinline__ unsigned short f2bf(float f) {
  union { __bf16 b; unsigned short u; } cv;
  cv.b = (__bf16)f;
  return cv.u;
}

__device__ __forceinline__ void st4(unsigned short* p, float a, float b, float c, float d) {
  ushort4 pk; pk.x = f2bf(a); pk.y = f2bf(b); pk.z = f2bf(c); pk.w = f2bf(d);
  *(ushort4*)p = pk;
}

__device__ __forceinline__ int reg3(int g) { return g >= 53 ? 2 : (g >= 49 ? 1 : 0); }

// ---------------- weight prep (blocks 0-767) + bias/mask table (blocks 768-1023) ----------------
__global__ __launch_bounds__(256) void k_prep(
    const float* __restrict__ qkv_w, const float* __restrict__ proj_w,
    const float* __restrict__ w1, const float* __restrict__ w2,
    const float* __restrict__ rpb,
    unsigned short* __restrict__ qkvwT, unsigned short* __restrict__ projwT,
    unsigned short* __restrict__ w1T, unsigned short* __restrict__ w2T,
    float* __restrict__ tbl)
{
  if (blockIdx.x < 768) {
    int idx = blockIdx.x * 256 + threadIdx.x;
    if (idx < 49152) {                       // qkv_w [128][384] -> qkvwT [384][128]
      int n = idx >> 7, k = idx & 127;
      qkvwT[idx] = f2bf(qkv_w[k * 384 + n]);
    } else if (idx < 65536) {                // proj_w [128][128] -> projwT [128][128]
      int i = idx - 49152; int n = i >> 7, k = i & 127;
      projwT[i] = f2bf(proj_w[k * 128 + n]);
    } else if (idx < 131072) {               // mlp_w1 [128][512] -> w1T [512][128]
      int i = idx - 65536; int n = i >> 7, k = i & 127;
      w1T[i] = f2bf(w1[k * 512 + n]);
    } else {                                 // mlp_w2 [512][128] -> w2T [128][512]
      int i = idx - 131072; int n = i >> 9, k = i & 511;
      w2T[i] = f2bf(w2[k * 128 + n]);
    }
  } else {
    int idx = (blockIdx.x - 768) * 256 + threadIdx.x;   // 65536 entries
    int kt = idx & 63, qt = (idx >> 6) & 63, h = (idx >> 12) & 3, cls = idx >> 14;
    float v;
    if (qt >= NTOK || kt >= NTOK) v = -3e38f;
    else {
      int qi = qt / 7, qj = qt % 7, ki = kt / 7, kj = kt % 7;
      int bi = (cls & 2) ? 49 : 0, bj = (cls & 1) ? 49 : 0;
      int rq = reg3(bi + qi) * 3 + reg3(bj + qj);
      int rk = reg3(bi + ki) * 3 + reg3(bj + kj);
      v = rpb[((qi - ki + 6) * 13 + (qj - kj + 6)) * HEADS + h] + (rq != rk ? -100.0f : 0.0f);
    }
    tbl[idx] = v;
  }
}

// ---------------- fused LN1 + window attention, 8 waves (512 thr) ----------------
// __launch_bounds__(512, 2): at 512 threads the 2nd arg acts as blocks/CU —
// (512,4) caps VGPR at 64 (round-6 spill). LDS (69.6 KB) already limits
// residency to 2 blocks/CU, so (512,2) lifts the cap to 128 for free.
__global__ __launch_bounds__(512, 2) void k_attn(
    const float* __restrict__ x,
    const float* __restrict__ n1w, const float* __restrict__ n1b,
    const unsigned short* __restrict__ qkvwT,
    const float* __restrict__ qkv_b,
    const unsigned short* __restrict__ projwT,
    const float* __restrict__ proj_b,
    const float* __restrict__ tbl,
    unsigned short* __restrict__ attn_out)
{
  __shared__ __align__(16) unsigned short s_x[64 * 136];   // x tile; then PV [token][d]
  __shared__ __align__(16) unsigned short s_qk[64 * 264];  // q|k [token][dim]; then P [qtok][ktok] per head
  __shared__ __align__(16) unsigned short s_vT[128 * 72];  // v^T [d][token]; then proj-out stage

  int tid = threadIdx.x;
  int wave = tid >> 6;          // 0..7
  int lane = tid & 63;
  int l = lane & 15, g = lane >> 4;
  int win = blockIdx.x;
  int wi = (win & 63) >> 3, wj = win & 7;
  int bi = win >> 6;

  // ---- phase 0: gather shifted rows of x, LN1 -> bf16 s_x; zero pad rows ----
  {
    float2 wv1 = *(const float2*)(n1w + lane * 2);
    float2 bv1 = *(const float2*)(n1b + lane * 2);
    float2 vr[7];
    #pragma unroll
    for (int rr = 0; rr < 7; ++rr) {       // issue all row loads up front
      int row = wave + rr * 8;
      if (row < NTOK) {
        int ti = row / 7, tj = row % 7;
        int i = wi * WS + ti + SHIFT; if (i >= HH) i -= HH;
        int j = wj * WS + tj + SHIFT; if (j >= WW2) j -= WW2;
        const float* xp = x + ((size_t)(bi * (HH * WW2) + i * WW2 + j)) * DIM;
        vr[rr] = *(const float2*)(xp + lane * 2);
      }
    }
    #pragma unroll
    for (int rr = 0; rr < 7; ++rr) {
      int row = wave + rr * 8;
      if (row < NTOK) {
        float2 v = vr[rr];
        float s = v.x + v.y, sq = v.x * v.x + v.y * v.y;
        #pragma unroll
        for (int off = 32; off; off >>= 1) {
          s += __shfl_xor(s, off);
          sq += __shfl_xor(sq, off);
        }
        float mean = s * (1.0f / DIM);
        float var = sq * (1.0f / DIM) - mean * mean;
        float rs = rsqrtf(var + 1e-5f);
        float y0 = (v.x - mean) * rs * wv1.x + bv1.x;
        float y1 = (v.y - mean) * rs * wv1.y + bv1.y;
        unsigned pack = ((unsigned)f2bf(y1) << 16) | (unsigned)f2bf(y0);
        *(unsigned*)&s_x[row * 136 + lane * 2] = pack;
      }
    }
  }
  for (int idx = tid; idx < 15 * 17; idx += 512) {
    int row = 49 + idx / 17, seg = idx % 17;
    *(uint4*)&s_x[row * 136 + seg * 8] = make_uint4(0, 0, 0, 0);
  }
  __syncthreads();

  // ---- phase 1: QKV^T GEMM: A=weights [wcol][k], B=x [token][k], D=[wcol][token] ----
  bf16x8 xf[4][4];   // [nt(token tile)][kk]
  #pragma unroll
  for (int nt = 0; nt < 4; ++nt)
    #pragma unroll
    for (int kk = 0; kk < 4; ++kk)
      xf[nt][kk] = *(const bf16x8*)&s_x[(nt * 16 + l) * 136 + kk * 32 + g * 8];

  #pragma unroll
  for (int wti = 0; wti < 3; ++wti) {
    int wt = wave * 3 + wti;                 // m-tile over 384 wcols, 0..23
    bf16x8 wf[4];
    #pragma unroll
    for (int kk = 0; kk < 4; ++kk)
      wf[kk] = *(const bf16x8*)(qkvwT + (size_t)(wt * 16 + l) * DIM + kk * 32 + g * 8);
    f32x4 acc[4];
    #pragma unroll
    for (int nt = 0; nt < 4; ++nt) acc[nt] = (f32x4){0.f, 0.f, 0.f, 0.f};
    #pragma unroll
    for (int kk = 0; kk < 4; ++kk)
      #pragma unroll
      for (int nt = 0; nt < 4; ++nt)
        acc[nt] = __builtin_amdgcn_mfma_f32_16x16x32_bf16(wf[kk], xf[nt][kk], acc[nt], 0, 0, 0);
    float4 b4 = *(const float4*)(qkv_b + wt * 16 + g * 4);
    if (wt < 16) {           // q (wt<8, cols 0-127) and k (cols 128-255): col = wt*16+g*4
      float sc = wt < 8 ? 0.17677669529663687f : 1.0f;
      #pragma unroll
      for (int nt = 0; nt < 4; ++nt)
        st4(&s_qk[(nt * 16 + l) * 264 + wt * 16 + g * 4],
            (acc[nt][0] + b4.x) * sc, (acc[nt][1] + b4.y) * sc,
            (acc[nt][2] + b4.z) * sc, (acc[nt][3] + b4.w) * sc);
    } else {                 // v -> v^T [d][token]
      int d0 = wt * 16 - 256 + g * 4;
      #pragma unroll
      for (int nt = 0; nt < 4; ++nt) {
        s_vT[(d0 + 0) * 72 + nt * 16 + l] = f2bf(acc[nt][0] + b4.x);
        s_vT[(d0 + 1) * 72 + nt * 16 + l] = f2bf(acc[nt][1] + b4.y);
        s_vT[(d0 + 2) * 72 + nt * 16 + l] = f2bf(acc[nt][2] + b4.z);
        s_vT[(d0 + 3) * 72 + nt * 16 + l] = f2bf(acc[nt][3] + b4.w);
      }
    }
  }
  __syncthreads();

  // ---- phase 2: S^T = K.Q^T, table C-init; in-reg softmax; P [qtok][ktok] ----
  int h = wave >> 1, qh = wave & 1;          // head, qtok-half
  bf16x8 kf[4], qf[2];
  #pragma unroll
  for (int mt = 0; mt < 4; ++mt)
    kf[mt] = *(const bf16x8*)&s_qk[(mt * 16 + l) * 264 + 128 + h * 32 + g * 8];
  #pragma unroll
  for (int nt2 = 0; nt2 < 2; ++nt2) {
    int nt = qh * 2 + nt2;
    qf[nt2] = *(const bf16x8*)&s_qk[(nt * 16 + l) * 264 + h * 32 + g * 8];
  }
  __syncthreads();   // all q/k fragment reads done; s_qk reusable as P

  int clsid = ((wi == 7) ? 2 : 0) | ((wj == 7) ? 1 : 0);
  const float* tb = tbl + ((clsid * 4 + h) << 12);
  f32x4 sc[4][2];    // [mt=ktok tile][nt2=qtok tile half]
  #pragma unroll
  for (int nt2 = 0; nt2 < 2; ++nt2) {
    int nt = qh * 2 + nt2;
    #pragma unroll
    for (int mt = 0; mt < 4; ++mt) {
      f32x4 ci = *(const f32x4*)(tb + (nt * 16 + l) * 64 + mt * 16 + g * 4);
      sc[mt][nt2] = __builtin_amdgcn_mfma_f32_16x16x32_bf16(kf[mt], qf[nt2], ci, 0, 0, 0);
    }
  }

  #pragma unroll
  for (int nt2 = 0; nt2 < 2; ++nt2) {
    int nt = qh * 2 + nt2;
    float m = sc[0][nt2][0];
    #pragma unroll
    for (int mt = 0; mt < 4; ++mt)
      #pragma unroll
      for (int rr = 0; rr < 4; ++rr) m = fmaxf(m, sc[mt][nt2][rr]);
    m = fmaxf(m, __shfl_xor(m, 16));
    m = fmaxf(m, __shfl_xor(m, 32));
    float ssum = 0.f;
    #pragma unroll
    for (int mt = 0; mt < 4; ++mt)
      #pragma unroll
      for (int rr = 0; rr < 4; ++rr) {
        float e = __expf(sc[mt][nt2][rr] - m);
        sc[mt][nt2][rr] = e;
        ssum += e;
      }
    ssum += __shfl_xor(ssum, 16);
    ssum += __shfl_xor(ssum, 32);
    float inv = 1.0f / ssum;
    #pragma unroll
    for (int mt = 0; mt < 4; ++mt)
      st4(&s_qk[(nt * 16 + l) * 264 + h * 64 + mt * 16 + g * 4],
          sc[mt][nt2][0] * inv, sc[mt][nt2][1] * inv, sc[mt][nt2][2] * inv, sc[mt][nt2][3] * inv);
  }
  __syncthreads();   // P is cross-wave now (PV reads all 4 nt per head)

  // ---- phase 3: PV^T: A=v^T [d][ktok], B=P [qtok][ktok], D=[d][qtok] -> s_x[token][d] ----
  int dt = qh;       // d-subtile within head
  bf16x8 vf[2], pf[4][2];
  #pragma unroll
  for (int kk = 0; kk < 2; ++kk)
    vf[kk] = *(const bf16x8*)&s_vT[(h * 32 + dt * 16 + l) * 72 + kk * 32 + g * 8];
  #pragma unroll
  for (int nt = 0; nt < 4; ++nt)
    #pragma unroll
    for (int kk = 0; kk < 2; ++kk)
      pf[nt][kk] = *(const bf16x8*)&s_qk[(nt * 16 + l) * 264 + h * 64 + kk * 32 + g * 8];
  #pragma unroll
  for (int nt = 0; nt < 4; ++nt) {
    f32x4 a = (f32x4){0.f, 0.f, 0.f, 0.f};
    a = __builtin_amdgcn_mfma_f32_16x16x32_bf16(vf[0], pf[nt][0], a, 0, 0, 0);
    a = __builtin_amdgcn_mfma_f32_16x16x32_bf16(vf[1], pf[nt][1], a, 0, 0, 0);
    st4(&s_x[(nt * 16 + l) * 136 + h * 32 + dt * 16 + g * 4], a[0], a[1], a[2], a[3]);
  }
  __syncthreads();

  // ---- phase 4: proj^T: A=projW^T [pcol][d], B=PV [token][d], D=[pcol][token] ----
  unsigned short* stage = s_vT;   // 64x136 fits in 128x72 region
  bf16x8 of[4][4];
  #pragma unroll
  for (int nt = 0; nt < 4; ++nt)
    #pragma unroll
    for (int kk = 0; kk < 4; ++kk)
      of[nt][kk] = *(const bf16x8*)&s_x[(nt * 16 + l) * 136 + kk * 32 + g * 8];
  {
    int wt = wave;               // 0..7 covers 128 pcols
    bf16x8 wf[4];
    #pragma unroll
    for (int kk = 0; kk < 4; ++kk)
      wf[kk] = *(const bf16x8*)(projwT + (size_t)(wt * 16 + l) * DIM + kk * 32 + g * 8);
    f32x4 acc[4];
    #pragma unroll
    for (int nt = 0; nt < 4; ++nt) acc[nt] = (f32x4){0.f, 0.f, 0.f, 0.f};
    #pragma unroll
    for (int kk = 0; kk < 4; ++kk)
      #pragma unroll
      for (int nt = 0; nt < 4; ++nt)
        acc[nt] = __builtin_amdgcn_mfma_f32_16x16x32_bf16(wf[kk], of[nt][kk], acc[nt], 0, 0, 0);
    float4 b4 = *(const float4*)(proj_b + wt * 16 + g * 4);
    #pragma unroll
    for (int nt = 0; nt < 4; ++nt)
      st4(&stage[(nt * 16 + l) * 136 + wt * 16 + g * 4],
          acc[nt][0] + b4.x, acc[nt][1] + b4.y, acc[nt][2] + b4.z, acc[nt][3] + b4.w);
  }
  __syncthreads();

  unsigned short* outp = attn_out + (size_t)win * (NTOK * DIM);
  for (int idx = tid; idx < NTOK * 16; idx += 512) {
    int row = idx >> 4, seg = idx & 15;
    *(uint4*)(outp + idx * 8) = *(const uint4*)&stage[row * 136 + seg * 8];
  }
}

// gelu via sigmoid form: 0.5x(1+tanh(y)) = x * sigmoid(2y), y = 0.79788456(x+0.044715x^3)
__device__ __forceinline__ float gelu_f(float x) {
  float x2 = x * x;
  float t = x * __builtin_fmaf(x2, -0.10294429f, -2.3022077f);
  float e = __builtin_amdgcn_exp2f(t);
  return x * __builtin_amdgcn_rcpf(1.0f + e);
}

// ---------------- fused residual+LN2+MLP, 4 waves (256 thr) ----------------
// io = z + gelu(ln2(z)@w1+b1)@w2 + b2, z = x + attn(gathered), z in registers.
// This round: (a) c-loop fully unrolled (compile-time buf + LDS offsets,
// cross-chunk scheduling); (b) GEMM2's wf2 loads issued AFTER GEMM1's loads
// and MFMAs, BEFORE the barrier — vmcnt drains in order, so issuing them
// first (round 4) forced GEMM1 to wait on them; issued last, GEMM1 waits only
// on wf and the wf2 latency is covered by gelu+store+barrier.
__global__ __launch_bounds__(256) void k_mlp(
    const float* __restrict__ x, const unsigned short* __restrict__ attn,
    const float* __restrict__ n2w, const float* __restrict__ n2b,
    const unsigned short* __restrict__ w1T, const float* __restrict__ b1,
    const unsigned short* __restrict__ w2T, const float* __restrict__ b2,
    float* __restrict__ io)
{
  __shared__ __align__(16) unsigned short s_t[2][64 * 136];
  __shared__ float s_part[64][4][2];
  int tid = threadIdx.x;
  int wave = tid >> 6;
  int lane = tid & 63;
  int l = lane & 15, g = lane >> 4;
  size_t m0 = (size_t)blockIdx.x * 64;
  int col0 = wave * 32 + g * 4;        // wti=0 col; wti=1 col = col0+16

  // ---- prologue: residual + LN2 ----
  float4 xz[4][2];
  float sA[4], sQ[4];
  #pragma unroll
  for (int nt = 0; nt < 4; ++nt) {
    int row = nt * 16 + l;
    int t = (int)m0 + row;
    int bi = t / (HH * WW2);
    int r = t % (HH * WW2);
    int i = r / WW2, j = r % WW2;
    int si = i >= SHIFT ? i - SHIFT : i + (HH - SHIFT);
    int sj = j >= SHIFT ? j - SHIFT : j + (WW2 - SHIFT);
    int win = bi * NWIN + (si / WS) * 8 + (sj / WS);
    int tok = (si % WS) * WS + (sj % WS);
    const float* xp = x + (size_t)t * DIM;
    const unsigned short* ap = attn + ((size_t)(win * NTOK + tok)) * DIM;
    float s = 0.f, sq = 0.f;
    #pragma unroll
    for (int wti = 0; wti < 2; ++wti) {
      int col = col0 + wti * 16;
      float4 xv = *(const float4*)(xp + col);
      ushort4 av = *(const ushort4*)(ap + col);
      float4 z;
      z.x = xv.x + __uint_as_float((unsigned)av.x << 16);
      z.y = xv.y + __uint_as_float((unsigned)av.y << 16);
      z.z = xv.z + __uint_as_float((unsigned)av.z << 16);
      z.w = xv.w + __uint_as_float((unsigned)av.w << 16);
      xz[nt][wti] = z;
      s += z.x + z.y + z.z + z.w;
      sq += z.x * z.x + z.y * z.y + z.z * z.z + z.w * z.w;
    }
    s += __shfl_xor(s, 16); s += __shfl_xor(s, 32);
    sq += __shfl_xor(sq, 16); sq += __shfl_xor(sq, 32);
    sA[nt] = s; sQ[nt] = sq;   // per-row partial over this wave's 32 cols
  }
  if (g == 0) {
    #pragma unroll
    for (int nt = 0; nt < 4; ++nt) {
      s_part[nt * 16 + l][wave][0] = sA[nt];
      s_part[nt * 16 + l][wave][1] = sQ[nt];
    }
  }
  __syncthreads();
  float4 wv0 = *(const float4*)(n2w + col0);
  float4 wv1 = *(const float4*)(n2w + col0 + 16);
  float4 bv0 = *(const float4*)(n2b + col0);
  float4 bv1 = *(const float4*)(n2b + col0 + 16);
  #pragma unroll
  for (int nt = 0; nt < 4; ++nt) {
    int row = nt * 16 + l;
    float s = 0.f, sq = 0.f;
    #pragma unroll
    for (int wv = 0; wv < 4; ++wv) { s += s_part[row][wv][0]; sq += s_part[row][wv][1]; }
    float mean = s * (1.0f / DIM);
    float var = sq * (1.0f / DIM) - mean * mean;
    float rs = rsqrtf(var + 1e-5f);
    float4 z0 = xz[nt][0], z1 = xz[nt][1];
    st4(&s_t[1][row * 136 + col0],
        (z0.x - mean) * rs * wv0.x + bv0.x, (z0.y - mean) * rs * wv0.y + bv0.y,
        (z0.z - mean) * rs * wv0.z + bv0.z, (z0.w - mean) * rs * wv0.w + bv0.w);
    st4(&s_t[1][row * 136 + col0 + 16],
        (z1.x - mean) * rs * wv1.x + bv1.x, (z1.y - mean) * rs * wv1.y + bv1.y,
        (z1.z - mean) * rs * wv1.z + bv1.z, (z1.w - mean) * rs * wv1.w + bv1.w);
  }
  __syncthreads();

  bf16x8 hf[4][4];
  #pragma unroll
  for (int nt = 0; nt < 4; ++nt)
    #pragma unroll
    for (int kk = 0; kk < 4; ++kk)
      hf[nt][kk] = *(const bf16x8*)&s_t[1][(nt * 16 + l) * 136 + kk * 32 + g * 8];

  f32x4 o[2][4];
  #pragma unroll
  for (int wti = 0; wti < 2; ++wti)
    #pragma unroll
    for (int nt = 0; nt < 4; ++nt) o[wti][nt] = (f32x4){0.f, 0.f, 0.f, 0.f};

  // Double-buffered s_t: first write into s_t[1] happens at c=1, after the c=0
  // barrier; writes to buffer p at chunk c+2 are fenced by barrier(c+1).
  #pragma unroll
  for (int c = 0; c < 4; ++c) {
    unsigned short* buf = s_t[c & 1];
    // GEMM1^T chunk: D[w1col][token], gelu, store buf[token][w1col-local]
    #pragma unroll
    for (int wti = 0; wti < 2; ++wti) {
      int wt = wave * 2 + wti;
      int n0 = c * 128 + wt * 16;
      bf16x8 wf[4];
      #pragma unroll
      for (int kk = 0; kk < 4; ++kk)
        wf[kk] = *(const bf16x8*)(w1T + (size_t)(n0 + l) * DIM + kk * 32 + g * 8);
      f32x4 acc[4];
      #pragma unroll
      for (int nt = 0; nt < 4; ++nt) acc[nt] = (f32x4){0.f, 0.f, 0.f, 0.f};
      #pragma unroll
      for (int kk = 0; kk < 4; ++kk)
        #pragma unroll
        for (int nt = 0; nt < 4; ++nt)
          acc[nt] = __builtin_amdgcn_mfma_f32_16x16x32_bf16(wf[kk], hf[nt][kk], acc[nt], 0, 0, 0);
      float4 b4 = *(const float4*)(b1 + n0 + g * 4);
      #pragma unroll
      for (int nt = 0; nt < 4; ++nt)
        st4(&buf[(nt * 16 + l) * 136 + wt * 16 + g * 4],
            gelu_f(acc[nt][0] + b4.x), gelu_f(acc[nt][1] + b4.y),
            gelu_f(acc[nt][2] + b4.z), gelu_f(acc[nt][3] + b4.w));
    }
    // issue GEMM2's weight loads now (after GEMM1's loads/MFMAs, before the
    // barrier): their L2 latency hides under gelu+store+barrier drain, and
    // GEMM1 never waits on them (in-order vmcnt).
    bf16x8 wf2r[2][4];
    #pragma unroll
    for (int wti = 0; wti < 2; ++wti)
      #pragma unroll
      for (int kk = 0; kk < 4; ++kk)
        wf2r[wti][kk] = *(const bf16x8*)(w2T + (size_t)((wave * 2 + wti) * 16 + l) * 512 + c * 128 + kk * 32 + g * 8);
    __syncthreads();
    // GEMM2^T chunk: o[pcol][token] += w2 chunk . t chunk  (reads buf; next
    // chunk's GEMM1 writes go to the other buffer, so no trailing barrier)
    #pragma unroll
    for (int kk = 0; kk < 4; ++kk) {
      bf16x8 tf[4];
      #pragma unroll
      for (int nt = 0; nt < 4; ++nt)
        tf[nt] = *(const bf16x8*)&buf[(nt * 16 + l) * 136 + kk * 32 + g * 8];
      #pragma unroll
      for (int wti = 0; wti < 2; ++wti)
        #pragma unroll
        for (int nt = 0; nt < 4; ++nt)
          o[wti][nt] = __builtin_amdgcn_mfma_f32_16x16x32_bf16(wf2r[wti][kk], tf[nt], o[wti][nt], 0, 0, 0);
    }
  }

  // ---- epilogue: io = z + mlp_out + b2, single store, no load ----
  #pragma unroll
  for (int wti = 0; wti < 2; ++wti) {
    int wt = wave * 2 + wti;
    float4 b4 = *(const float4*)(b2 + wt * 16 + g * 4);
    #pragma unroll
    for (int nt = 0; nt < 4; ++nt) {
      float4 z = xz[nt][wti];
      float4 pv;
      pv.x = z.x + o[wti][nt][0] + b4.x;
      pv.y = z.y + o[wti][nt][1] + b4.y;
      pv.z = z.z + o[wti][nt][2] + b4.z;
      pv.w = z.w + o[wti][nt][3] + b4.w;
      *(float4*)(io + (m0 + nt * 16 + l) * DIM + wt * 16 + g * 4) = pv;
    }
  }
}

extern "C" void kernel_launch(void* const* d_in, const int* in_sizes, int n_in,
                              void* d_out, int out_size, void* d_ws, size_t ws_size,
                              hipStream_t stream) {
  const float* x       = (const float*)d_in[0];
  const float* qkv_w   = (const float*)d_in[1];
  const float* qkv_b   = (const float*)d_in[2];
  const float* proj_w  = (const float*)d_in[3];
  const float* proj_b  = (const float*)d_in[4];
  const float* rpb     = (const float*)d_in[5];
  const float* n1w     = (const float*)d_in[6];
  const float* n1b     = (const float*)d_in[7];
  const float* n2w     = (const float*)d_in[8];
  const float* n2b     = (const float*)d_in[9];
  const float* mlp_w1  = (const float*)d_in[10];
  const float* mlp_b1  = (const float*)d_in[11];
  const float* mlp_w2  = (const float*)d_in[12];
  const float* mlp_b2  = (const float*)d_in[13];
  float* out = (float*)d_out;

  char* ws = (char*)d_ws;
  const size_t TOKB = (size_t)TOKENS * DIM * 2;     // 51,380,224 B
  unsigned short* attn_o = (unsigned short*)(ws);
  unsigned short* qkvwT  = (unsigned short*)(ws + TOKB);
  unsigned short* projwT = (unsigned short*)(ws + TOKB + 98304);
  unsigned short* w1T    = (unsigned short*)(ws + TOKB + 98304 + 32768);
  unsigned short* w2T    = (unsigned short*)(ws + TOKB + 98304 + 32768 + 131072);
  float*          tbl    = (float*)(ws + TOKB + 98304 + 32768 + 131072 + 131072);  // 262144 B

  k_prep<<<1024, 256, 0, stream>>>(qkv_w, proj_w, mlp_w1, mlp_w2, rpb,
                                   qkvwT, projwT, w1T, w2T, tbl);
  k_attn<<<WINDOWS, 512, 0, stream>>>(x, n1w, n1b, qkvwT, qkv_b, projwT, proj_b, tbl, attn_o);
  k_mlp<<<TOKENS / 64, 256, 0, stream>>>(x, attn_o, n2w, n2b, w1T, mlp_b1, w2T, mlp_b2, out);
}